// Round 2
// baseline (423.394 us; speedup 1.0000x reference)
//
#include <hip/hip_runtime.h>
#include <cstdint>
#include <cstddef>

typedef unsigned short u16;
typedef __attribute__((ext_vector_type(8))) short short8;
typedef __attribute__((ext_vector_type(4))) float floatx4;
typedef __attribute__((ext_vector_type(2))) float floatx2;
typedef __attribute__((ext_vector_type(4))) unsigned int uintx4;
typedef __attribute__((ext_vector_type(2))) unsigned int uintx2;
typedef __attribute__((ext_vector_type(2))) __bf16 bf16x2;

#define LOG2E 1.44269504f

__device__ __forceinline__ float bf2f(u16 u){
  union { unsigned int i; float f; } v; v.i = ((unsigned int)u) << 16; return v.f;
}
__device__ __forceinline__ u16 f2bf(float f){
  union { __bf16 b; u16 u; } v; v.b = (__bf16)f; return v.u;
}
// packed f32x2 -> bf16x2 (v_cvt_pk_bf16_f32, RNE)
__device__ __forceinline__ unsigned int pk2(float a, float b){
  union { bf16x2 h; unsigned int u; } v;
  v.h = __builtin_convertvector((floatx2){a, b}, bf16x2);
  return v.u;
}
// async global->LDS, 16B per lane (dest = wave-uniform base + lane*16)
__device__ __forceinline__ void gload16(const void* g, void* l){
  __builtin_amdgcn_global_load_lds((const __attribute__((address_space(1))) unsigned int*)g,
                                   (__attribute__((address_space(3))) unsigned int*)l, 16, 0, 0);
}
// load 8 fp32 from g, convert to 8 bf16 packed in a uintx4
__device__ __forceinline__ uintx4 ld8f_bf(const float* g){
  floatx4 u0 = *(const floatx4*)g;
  floatx4 u1 = *(const floatx4*)(g + 4);
  uintx4 w;
  w.x = pk2(u0.x, u0.y); w.y = pk2(u0.z, u0.w);
  w.z = pk2(u1.x, u1.y); w.w = pk2(u1.z, u1.w);
  return w;
}
__device__ __forceinline__ float redq(float v){   // sum across quads (lanes ^16, ^32)
  v += __shfl_xor(v, 16); v += __shfl_xor(v, 32);
  return v;
}

// ---------------- prep kernels ----------------
__global__ void transpose_w(const float* __restrict__ qkv_w, const float* __restrict__ anchor_w,
                            const float* __restrict__ proj_w,
                            u16* __restrict__ qkvt, u16* __restrict__ anct, u16* __restrict__ projt){
  int id = blockIdx.x*256 + threadIdx.x;
  if (id < 196608){ int k = id / 768, n = id % 768; qkvt[n*256 + k] = f2bf(qkv_w[id]); }
  else if (id < 229376){ int r = id - 196608; int k = r / 128, n = r % 128; anct[n*256 + k] = f2bf(anchor_w[r]); }
  else { int r = id - 229376; int k = r >> 8, n = r & 255; projt[n*256 + k] = f2bf(proj_w[r]); }
}

__global__ void cpb_mlp(const float* __restrict__ tw, const float* __restrict__ ts,
                        const float* __restrict__ w1w, const float* __restrict__ b1w, const float* __restrict__ w2w,
                        const float* __restrict__ w1s1, const float* __restrict__ b1s1, const float* __restrict__ w2s1,
                        const float* __restrict__ w1s2, const float* __restrict__ b1s2, const float* __restrict__ w2s2,
                        float* __restrict__ btw, float* __restrict__ bts1, float* __restrict__ bts2){
  int tag = blockIdx.y;
  const float *tab, *w1, *b1, *w2; float* bt; int T;
  if (tag == 0){ tab = tw; w1 = w1w;  b1 = b1w;  w2 = w2w;  bt = btw;  T = 961; }
  else if (tag == 1){ tab = ts; w1 = w1s1; b1 = b1s1; w2 = w2s1; bt = bts1; T = 1521; }
  else { tab = ts; w1 = w1s2; b1 = b1s2; w2 = w2s2; bt = bts2; T = 1521; }
  __shared__ float sw1[2][512];
  __shared__ float sb1[512];
  __shared__ float sw2[512][4];
  for (int j = threadIdx.x; j < 512; j += 256){
    sw1[0][j] = w1[j]; sw1[1][j] = w1[512 + j]; sb1[j] = b1[j];
    for (int h = 0; h < 4; ++h) sw2[j][h] = w2[j*4 + h];
  }
  __syncthreads();
  int idx = blockIdx.x*256 + threadIdx.x;
  int r = idx >> 2, hh = idx & 3;
  if (r < T){
    float t0 = tab[2*r], t1 = tab[2*r + 1];
    float acc = 0.f;
    for (int j = 0; j < 512; ++j){
      float hj = fmaxf(fmaf(t0, sw1[0][j], fmaf(t1, sw1[1][j], sb1[j])), 0.f);
      acc = fmaf(hj, sw2[j][hh], acc);
    }
    bt[r*4 + hh] = acc;
  }
}

// bias tables pre-folded: store (16*sigmoid(v) - off_h) * log2(e), off_h = min(scale_h+16, 80)
__global__ void bias_gather(const float* __restrict__ btw, const float* __restrict__ bts1,
                            const float* __restrict__ bts2,
                            const int* __restrict__ idxw, const int* __restrict__ idxa2w,
                            const int* __restrict__ idxw2a,
                            const float* __restrict__ lsw, const float* __restrict__ ls1,
                            const float* __restrict__ ls2,
                            float* __restrict__ bw, float* __restrict__ bs1, float* __restrict__ bs2){
  int id = blockIdx.x*256 + threadIdx.x;     // 3 * 262144
  int which = id >> 18;
  int rem = id & 262143;
  int h = rem >> 16, e = rem & 65535;
  const float* bt; const int* ix; float* dst; const float* ls;
  if (which == 0){ bt = btw;  ix = idxw;   dst = bw;  ls = lsw; }
  else if (which == 1){ bt = bts1; ix = idxa2w; dst = bs1; ls = ls1; }
  else { bt = bts2; ix = idxw2a; dst = bs2; ls = ls2; }
  float v = bt[ix[e]*4 + h];
  float scale = exp2f(fminf(ls[h], 4.6051702f) * LOG2E);
  float off = fminf(scale + 16.f, 80.f);
  float sig = 16.f / (1.f + exp2f(-v * LOG2E));
  dst[h*65536 + e] = (sig - off) * LOG2E;
}

__global__ void avgpool(const float* __restrict__ x, float* __restrict__ pooled){
  int a = blockIdx.x, c = threadIdx.x;
  int ay = a >> 6, ax = a & 63;
  float acc = 0.f;
#pragma unroll
  for (int dy = 0; dy < 4; ++dy)
#pragma unroll
    for (int dx = 0; dx < 4; ++dx)
      acc += x[(size_t)((ay*4 + dy)*256 + ax*4 + dx)*256 + c];
  pooled[(size_t)a*256 + c] = acc * 0.0625f;
}

// ---------------- qkv GEMM with fused epilogue ----------------
// blockIdx.y = 0/1 : C[:, y*128 .. y*128+128) = L2norm_perhead( A @ Bt[y]^T + bias[y] ), bf16
// blockIdx.y = 2   : VTg[col][row] = (A @ Bt[2]^T + bias[2])^T, bf16 (transposed V, stride 32768)
__launch_bounds__(256, 2)
__global__ void gemm_qkv(const float* __restrict__ A, const u16* __restrict__ Bt,
                         const float* __restrict__ bias, u16* __restrict__ C,
                         u16* __restrict__ VTg, int N, int K){
  __shared__ __align__(16) u16 lsA[4096];   // [4 kq][128 rows][8], +2-row skew per kq
  __shared__ __align__(16) u16 lsB[4096];   // [128 rows][32 k] linear (global_load_lds dest)
  const int tid = threadIdx.x, lane = tid & 63, wv = tid >> 6;
  const int lane15 = lane & 15, quad = lane >> 4;
  const int wr = wv >> 1, wc = wv & 1;
  const int m0 = blockIdx.x * 128;
  const int y = blockIdx.y;
  const bool vmode = (y == 2);
  const u16* Btb = Bt + (size_t)y*128*K;
  const float* bb = bias + y*128;
  char* lsBb = (char*)lsB;
  const int brow = wv*16 + (lane >> 2);
  const u16* bsrc = Btb + (size_t)brow*K + (lane & 3)*8;
  const int arow = tid & 127, aq = tid >> 7;          // this thread stages kq = aq and aq+2
  const float* asrc = A + (size_t)(m0 + arow)*K;
  const int aslot0 = aq*1024 + ((arow + aq*2) & 127)*8;
  const int aslot1 = (aq+2)*1024 + ((arow + (aq+2)*2) & 127)*8;
  floatx4 acc[4][4] = {};
  for (int k0 = 0; k0 < K; k0 += 32){
    gload16(bsrc + k0,                 lsBb + wv*1024);          // rows 0..63
    gload16(bsrc + (size_t)64*K + k0,  lsBb + 4096 + wv*1024);   // rows 64..127
    uintx4 ra0 = ld8f_bf(asrc + k0 + aq*8);
    uintx4 ra1 = ld8f_bf(asrc + k0 + (aq+2)*8);
    *(uintx4*)(lsA + aslot0) = ra0;
    *(uintx4*)(lsA + aslot1) = ra1;
    __syncthreads();
    short8 a[4], b[4];
#pragma unroll
    for (int i = 0; i < 4; ++i){
      int r = wr*64 + i*16 + lane15;
      a[i] = *(const short8*)(lsA + quad*1024 + ((r + quad*2) & 127)*8);
    }
#pragma unroll
    for (int j = 0; j < 4; ++j)
      b[j] = *(const short8*)(lsBb + (wc*64 + j*16 + lane15)*64 + quad*16);
    if (!vmode){
#pragma unroll
      for (int i = 0; i < 4; ++i)
#pragma unroll
        for (int j = 0; j < 4; ++j)
          acc[i][j] = __builtin_amdgcn_mfma_f32_16x16x32_bf16(b[j], a[i], acc[i][j], 0, 0, 0);
    } else {
#pragma unroll
      for (int i = 0; i < 4; ++i)
#pragma unroll
        for (int j = 0; j < 4; ++j)
          acc[i][j] = __builtin_amdgcn_mfma_f32_16x16x32_bf16(a[i], b[j], acc[i][j], 0, 0, 0);
    }
    __syncthreads();
  }
  if (vmode){
    // acc[i][j][r]: row = m0+wr*64+i*16+quad*4+r, col = wc*64+j*16+lane15
#pragma unroll
    for (int j = 0; j < 4; ++j){
      int col = wc*64 + j*16 + lane15;
      float bz = bb[col];
#pragma unroll
      for (int i = 0; i < 4; ++i){
        int rowb = m0 + wr*64 + i*16 + quad*4;
        uintx2 w;
        w.x = pk2(acc[i][j][0] + bz, acc[i][j][1] + bz);
        w.y = pk2(acc[i][j][2] + bz, acc[i][j][3] + bz);
        *(uintx2*)(VTg + (size_t)col*32768 + rowb) = w;
      }
    }
  } else {
    // acc[i][j][r]: row = m0+wr*64+i*16+lane15, col = wc*64+j*16+quad*4+r
#pragma unroll
    for (int j = 0; j < 4; ++j){
      floatx4 bz = *(const floatx4*)(bb + wc*64 + j*16 + quad*4);
#pragma unroll
      for (int i = 0; i < 4; ++i) acc[i][j] += bz;
    }
    // per-(row, 32-col head) L2 normalization: sum over j-pair, r, and quads
#pragma unroll
    for (int i = 0; i < 4; ++i){
#pragma unroll
      for (int jp = 0; jp < 2; ++jp){
        floatx4 s2 = acc[i][jp*2]*acc[i][jp*2] + acc[i][jp*2+1]*acc[i][jp*2+1];
        float ss = (s2.x + s2.y) + (s2.z + s2.w);
        ss = redq(ss);
        float inv = 1.f / fmaxf(sqrtf(ss), 1e-12f);
        acc[i][jp*2]   *= inv;
        acc[i][jp*2+1] *= inv;
      }
    }
#pragma unroll
    for (int i = 0; i < 4; ++i){
      int row = m0 + wr*64 + i*16 + lane15;
#pragma unroll
      for (int j = 0; j < 4; ++j){
        int colb = y*128 + wc*64 + j*16 + quad*4;
        uintx2 w;
        w.x = pk2(acc[i][j][0], acc[i][j][1]);
        w.y = pk2(acc[i][j][2], acc[i][j][3]);
        *(uintx2*)(C + (size_t)row*N + colb) = w;
      }
    }
  }
}

// ---------------- in-place proj GEMM: AC[M,256](f32) <- AC @ Bt^T + bias ----------------
__launch_bounds__(256, 2)
__global__ void gemm_proj_inplace(float* __restrict__ AC, const u16* __restrict__ Bt,
                                  const float* __restrict__ bias){
  __shared__ __align__(16) u16 lsA[4096];   // [4 kq][128][8], skewed
  __shared__ __align__(16) u16 lsB[8192];   // [256 rows][32 k] linear
  const int tid = threadIdx.x, lane = tid & 63, wv = tid >> 6;
  const int lane15 = lane & 15, quad = lane >> 4;
  const int wr = wv >> 1, wc = wv & 1;     // wave = 64 rows x 128 cols
  const int m0 = blockIdx.x * 128;
  char* lsBb = (char*)lsB;
  const int brow = wv*16 + (lane >> 2);
  const u16* bsrc = Bt + (size_t)brow*256 + (lane & 3)*8;
  const int arow = tid & 127, aq = tid >> 7;
  const float* asrc = AC + (size_t)(m0 + arow)*256;
  const int aslot0 = aq*1024 + ((arow + aq*2) & 127)*8;
  const int aslot1 = (aq+2)*1024 + ((arow + (aq+2)*2) & 127)*8;
  floatx4 acc[4][8] = {};
  for (int k0 = 0; k0 < 256; k0 += 32){
    gload16(bsrc + k0,                lsBb +         wv*1024);
    gload16(bsrc + 64*256 + k0,       lsBb + 4096  + wv*1024);
    gload16(bsrc + 128*256 + k0,      lsBb + 8192  + wv*1024);
    gload16(bsrc + 192*256 + k0,      lsBb + 12288 + wv*1024);
    uintx4 ra0 = ld8f_bf(asrc + k0 + aq*8);
    uintx4 ra1 = ld8f_bf(asrc + k0 + (aq+2)*8);
    *(uintx4*)(lsA + aslot0) = ra0;
    *(uintx4*)(lsA + aslot1) = ra1;
    __syncthreads();
    short8 a[4], b[8];
#pragma unroll
    for (int i = 0; i < 4; ++i){
      int r = wr*64 + i*16 + lane15;
      a[i] = *(const short8*)(lsA + quad*1024 + ((r + quad*2) & 127)*8);
    }
#pragma unroll
    for (int j = 0; j < 8; ++j)
      b[j] = *(const short8*)(lsBb + (wc*128 + j*16 + lane15)*64 + quad*16);
#pragma unroll
    for (int i = 0; i < 4; ++i)
#pragma unroll
      for (int j = 0; j < 8; ++j)
        acc[i][j] = __builtin_amdgcn_mfma_f32_16x16x32_bf16(b[j], a[i], acc[i][j], 0, 0, 0);
    __syncthreads();
  }
#pragma unroll
  for (int i = 0; i < 4; ++i){
    int row = m0 + wr*64 + i*16 + lane15;
#pragma unroll
    for (int j = 0; j < 8; ++j){
      int colb = wc*128 + j*16 + quad*4;
      floatx4 bz = *(const floatx4*)(bias + colb);
      floatx4 o = acc[i][j] + bz;
      *(floatx4*)(AC + (size_t)row*256 + colb) = o;
    }
  }
}

// ---------------- window attention (S^T formulation) ----------------
// qkvh: [32768][256] bf16 (Q norm 0..127, K norm 128..255); vt: [128][32768] bf16 V^T
// grid (128 windows, 4 heads)
__launch_bounds__(256, 3)
__global__ void win_attn(const u16* __restrict__ qkvh, const u16* __restrict__ vt,
                         const float* __restrict__ lsw,
                         const float* __restrict__ biasw, float* __restrict__ outm, int r0){
  __shared__ __align__(16) u16 sm[16384];   // 32 KB: K[0,8192) Q->P[8192,16384)
  const int tid = threadIdx.x, lane = tid & 63, wv = tid >> 6;
  const int lane15 = lane & 15, quad = lane >> 4;
  const int h = blockIdx.y;
  const int wyl = blockIdx.x >> 4, wx = blockIdx.x & 15;
  u16* Ks = sm;
  u16* Qs = sm + 8192;
  { // DMA stage Q,K (pre-normalized bf16) into k-outer layout [kq][256 tok][8]
    int tok = wv*64 + lane;
    int row = (wyl*16 + (tok >> 4))*256 + wx*16 + (tok & 15);
    const char* src = (const char*)(qkvh + (size_t)row*256) + h*64;
    char* qd = (char*)Qs + wv*1024;
    char* kd = (char*)Ks + wv*1024;
#pragma unroll
    for (int kq = 0; kq < 4; ++kq){
      gload16(src + kq*16,        qd + kq*4096);
      gload16(src + 256 + kq*16,  kd + kq*4096);
    }
  }
  __syncthreads();
  short8 qf[4];                 // wave owns queries wv*64 .. +63 (B-operand)
#pragma unroll
  for (int j = 0; j < 4; ++j)
    qf[j] = *(const short8*)(Qs + quad*2048 + (wv*64 + j*16 + lane15)*8);
  __syncthreads();              // all Q reads done before P overwrites

  float scale = exp2f(fminf(lsw[h], 4.6051702f) * LOG2E) * LOG2E;
  const float* bptr = biasw + ((size_t)h << 16);
  const u16* vbase = vt + (size_t)(h*32)*32768;
  u16* Pw = Qs + wv*2048;       // per-wave P^T: [4 key-octs][64 queries][8]
  const floatx4 zf4 = {0.f, 0.f, 0.f, 0.f};
  floatx4 accO[2][4] = {};      // O^T: [d-tile][query-tile]
  float lsum[4] = {};

  for (int kc = 0; kc < 8; ++kc){      // 32 keys per chunk
    // V^T fragments straight from global (L2): keys kc*32+quad*8+e, d = m*16+lane15
    int key0 = kc*32 + quad*8;
    int krow = (wyl*16 + (key0 >> 4))*256 + wx*16 + (key0 & 15);
    short8 vtf[2];
#pragma unroll
    for (int m = 0; m < 2; ++m)
      vtf[m] = *(const short8*)(vbase + (size_t)(m*16 + lane15)*32768 + krow);
    floatx4 bia[2][4];
#pragma unroll
    for (int i = 0; i < 2; ++i)
#pragma unroll
      for (int j = 0; j < 4; ++j)
        bia[i][j] = *(const floatx4*)(bptr + (size_t)(wv*64 + j*16 + lane15)*256 + kc*32 + i*16 + quad*4);
    short8 kf[2];
#pragma unroll
    for (int i = 0; i < 2; ++i)
      kf[i] = *(const short8*)(Ks + quad*2048 + (kc*32 + i*16 + lane15)*8);
#pragma unroll
    for (int i = 0; i < 2; ++i)
#pragma unroll
      for (int j = 0; j < 4; ++j){
        floatx4 sv = __builtin_amdgcn_mfma_f32_16x16x32_bf16(kf[i], qf[j], zf4, 0, 0, 0);
        float p0 = exp2f(fmaf(sv[0], scale, bia[i][j][0]));
        float p1 = exp2f(fmaf(sv[1], scale, bia[i][j][1]));
        float p2 = exp2f(fmaf(sv[2], scale, bia[i][j][2]));
        float p3 = exp2f(fmaf(sv[3], scale, bia[i][j][3]));
        lsum[j] += (p0 + p1) + (p2 + p3);
        uintx2 w; w.x = pk2(p0, p1); w.y = pk2(p2, p3);
        *(uintx2*)(Pw + (i*2 + (quad>>1))*512 + (j*16 + lane15)*8 + (quad&1)*4) = w;
      }
    asm volatile("s_waitcnt lgkmcnt(0)" ::: "memory");
    short8 ptf[4];
#pragma unroll
    for (int j = 0; j < 4; ++j)
      ptf[j] = *(const short8*)(Pw + quad*512 + (j*16 + lane15)*8);
#pragma unroll
    for (int m = 0; m < 2; ++m)
#pragma unroll
      for (int j = 0; j < 4; ++j)
        accO[m][j] = __builtin_amdgcn_mfma_f32_16x16x32_bf16(vtf[m], ptf[j], accO[m][j], 0, 0, 0);
  }
  float linv[4];
#pragma unroll
  for (int j = 0; j < 4; ++j) linv[j] = 1.f / redq(lsum[j]);
#pragma unroll
  for (int m = 0; m < 2; ++m)
#pragma unroll
    for (int j = 0; j < 4; ++j){
      int tok = wv*64 + j*16 + lane15;
      int py = r0 + wyl*16 + (tok >> 4), px = wx*16 + (tok & 15);
      floatx4 o = accO[m][j] * linv[j];
      *(floatx4*)(outm + (size_t)(py*256 + px)*256 + h*32 + m*16 + quad*4) = o;
    }
}

// ---------------- stripe phase 1: xm partials (key-split) ----------------
// grid (32 stripes, 4 heads, 2 key-halves)
__launch_bounds__(256, 3)
__global__ void stripe_xm(const u16* __restrict__ qkvh, const u16* __restrict__ vt,
                          const u16* __restrict__ anchor,
                          const float* __restrict__ ls1, const float* __restrict__ bias1,
                          float* __restrict__ gl1, u16* __restrict__ gO, int r0){
  __shared__ __align__(16) u16 sm[18432];  // 36 KB: ANC[0,2048) KC0[2048,6144) KC1[6144,10240) P1T[10240,18432)
  const int tid = threadIdx.x, lane = tid & 63, wv = tid >> 6;
  const int lane15 = lane & 15, quad = lane >> 4;
  const int s = blockIdx.x, h = blockIdx.y, kb = blockIdx.z;
  const int syl = s >> 3, sx = s & 7;
  u16* ANC = sm; u16* P1T = sm + 10240;
  if (wv == 0){   // anchors pre-normalized in anch
    int ay = (r0 >> 2) + syl*8 + (lane >> 3), ax = sx*8 + (lane & 7);
    const char* asrc = (const char*)(anchor + (size_t)(ay*64 + ax)*128) + h*64;
#pragma unroll
    for (int kq = 0; kq < 4; ++kq)
      gload16(asrc + kq*16, (char*)ANC + kq*1024);
  }
  // K chunk staging: wave wv stages kq=wv for 128 tokens (2 gloads)
  auto stageK = [&](int kc, int buf){
    int kkb = kb*512 + kc*128;
    char* KC = (char*)(sm + 2048 + buf*4096);
#pragma unroll
    for (int hf = 0; hf < 2; ++hf){
      int tok = kkb + hf*64 + lane;
      int row = (syl*32 + (tok >> 5))*256 + sx*32 + (tok & 31);
      gload16((const char*)(qkvh + (size_t)row*256) + 256 + h*64 + wv*16,
              KC + wv*2048 + hf*1024);
    }
  };
  stageK(0, 0);
  __syncthreads();
  short8 ancf = *(const short8*)(ANC + quad*512 + (wv*16 + lane15)*8);   // wave's 16 anchors (B-side)
  float scale1 = exp2f(fminf(ls1[h], 4.6051702f) * LOG2E) * LOG2E;
  const float* b1p = bias1 + ((size_t)h << 16) + (size_t)(wv*16 + lane15)*1024;
  const u16* vbase = vt + (size_t)(h*32)*32768;
  const floatx4 zf4 = {0.f, 0.f, 0.f, 0.f};
  floatx4 accO1[2] = {};
  float l1 = 0.f;
  for (int kc = 0; kc < 4; ++kc){
    if (kc < 3) stageK(kc + 1, (kc + 1) & 1);   // prefetch next chunk, overlaps compute
    int kkb = kb*512 + kc*128;
    const u16* KC = sm + 2048 + (kc & 1)*4096;
    // prefetch V^T fragments for this chunk (global/L2)
    short8 vfrag[4][2];
#pragma unroll
    for (int ks = 0; ks < 4; ++ks){
      int key0 = kkb + (ks*4 + quad)*8;
      int krow = (syl*32 + (key0 >> 5))*256 + sx*32 + (key0 & 31);
#pragma unroll
      for (int m = 0; m < 2; ++m)
        vfrag[ks][m] = *(const short8*)(vbase + (size_t)(m*16 + lane15)*32768 + krow);
    }
    floatx4 bia[8];
#pragma unroll
    for (int i = 0; i < 8; ++i)
      bia[i] = *(const floatx4*)(b1p + kkb + i*16 + quad*4);
#pragma unroll
    for (int i = 0; i < 8; ++i){
      short8 kf = *(const short8*)(KC + quad*1024 + (i*16 + lane15)*8);
      floatx4 sv = __builtin_amdgcn_mfma_f32_16x16x32_bf16(kf, ancf, zf4, 0, 0, 0);
      float p0 = exp2f(fmaf(sv[0], scale1, bia[i][0]));
      float p1 = exp2f(fmaf(sv[1], scale1, bia[i][1]));
      float p2 = exp2f(fmaf(sv[2], scale1, bia[i][2]));
      float p3 = exp2f(fmaf(sv[3], scale1, bia[i][3]));
      l1 += (p0 + p1) + (p2 + p3);
      uintx2 w; w.x = pk2(p0, p1); w.y = pk2(p2, p3);
      *(uintx2*)(P1T + (i*2 + (quad>>1))*512 + (wv*16 + lane15)*8 + (quad&1)*4) = w;
    }
    asm volatile("s_waitcnt lgkmcnt(0)" ::: "memory");
#pragma unroll
    for (int ks = 0; ks < 4; ++ks){
      short8 ptf = *(const short8*)(P1T + (ks*4 + quad)*512 + (wv*16 + lane15)*8);
#pragma unroll
      for (int m = 0; m < 2; ++m)
        accO1[m] = __builtin_amdgcn_mfma_f32_16x16x32_bf16(vfrag[ks][m], ptf, accO1[m], 0, 0, 0);
    }
    __syncthreads();   // drains vmcnt: next-chunk DMA landed; this chunk's LDS reads done
  }
  l1 = redq(l1);
  int ent = (s*4 + h)*2 + kb;
  if (quad == 0) gl1[ent*64 + wv*16 + lane15] = l1;
#pragma unroll
  for (int m = 0; m < 2; ++m){
    uintx2 w; w.x = pk2(accO1[m][0], accO1[m][1]); w.y = pk2(accO1[m][2], accO1[m][3]);
    *(uintx2*)(gO + (size_t)ent*2048 + (wv*16 + lane15)*32 + m*16 + quad*4) = w;
  }
}

// ---------------- stripe phase 2: xs ----------------
// grid (32 stripes * 4 query-chunks, 4 heads)
__launch_bounds__(256, 3)
__global__ void stripe_xs(const u16* __restrict__ qkvh, const u16* __restrict__ anchor,
                          const float* __restrict__ ls2, const float* __restrict__ bias2,
                          const float* __restrict__ gl1, const u16* __restrict__ gO,
                          float* __restrict__ outm, int r0){
  __shared__ __align__(16) u16 sm[20480]; // ANC[0,2048) XMT[2048,4096) QW[4096+wv*2048) P2T[12288+wv*2048)
  const int tid = threadIdx.x, lane = tid & 63, wv = tid >> 6;
  const int lane15 = lane & 15, quad = lane >> 4;
  const int s = blockIdx.x >> 2, qc = blockIdx.x & 3, h = blockIdx.y;
  const int syl = s >> 3, sx = s & 7;
  u16* ANC = sm;
  u16* XMT = sm + 2048;
  u16* QW  = sm + 4096 + wv*2048;
  u16* P2T = sm + 12288 + wv*2048;
  if (wv == 0){
    int ay = (r0 >> 2) + syl*8 + (lane >> 3), ax = sx*8 + (lane & 7);
    const char* asrc = (const char*)(anchor + (size_t)(ay*64 + ax)*128) + h*64;
#pragma unroll
    for (int kq = 0; kq < 4; ++kq)
      gload16(asrc + kq*16, (char*)ANC + kq*1024);
  }
  { // combine xm partials -> XMT [anchor-oct][d 32][8] bf16
    int a = tid >> 2, db = (tid & 3)*8;
    int e0 = (s*4 + h)*2;
    float inv = 1.f / (gl1[e0*64 + a] + gl1[(e0 + 1)*64 + a]);
    uintx4 u0 = *(const uintx4*)(gO + (size_t)e0*2048 + a*32 + db);
    uintx4 u1 = *(const uintx4*)(gO + (size_t)(e0 + 1)*2048 + a*32 + db);
    unsigned int w0[4] = {u0.x, u0.y, u0.z, u0.w};
    unsigned int w1[4] = {u1.x, u1.y, u1.z, u1.w};
#pragma unroll
    for (int c = 0; c < 4; ++c){
      float a0 = bf2f((u16)(w0[c] & 0xffffu)) + bf2f((u16)(w1[c] & 0xffffu));
      float a1 = bf2f((u16)(w0[c] >> 16))     + bf2f((u16)(w1[c] >> 16));
      XMT[(a >> 3)*256 + (db + c*2)*8     + (a & 7)] = f2bf(a0 * inv);
      XMT[(a >> 3)*256 + (db + c*2 + 1)*8 + (a & 7)] = f2bf(a1 * inv);
    }
  }
  int tq = qc*256 + wv*64;     // query base within stripe (wave owns 64)
  { // DMA stage this wave's 64 queries (pre-normalized)
    int tok = tq + lane;
    int row = (syl*32 + (tok >> 5))*256 + sx*32 + (tok & 31);
    const char* src = (const char*)(qkvh + (size_t)row*256) + h*64;
#pragma unroll
    for (int kq = 0; kq < 4; ++kq)
      gload16(src + kq*16, (char*)QW + kq*1024);
  }
  __syncthreads();
  short8 qf2[4];
#pragma unroll
  for (int j = 0; j < 4; ++j)
    qf2[j] = *(const short8*)(QW + quad*512 + (j*16 + lane15)*8);
  float scale2 = exp2f(fminf(ls2[h], 4.6051702f) * LOG2E) * LOG2E;
  const float* b2p = bias2 + ((size_t)h << 16);
  const floatx4 zf4 = {0.f, 0.f, 0.f, 0.f};
  floatx4 accO2[2][4] = {};
  float l2[4] = {};
#pragma unroll
  for (int c = 0; c < 2; ++c){      // 2 anchor chunks of 32
    floatx4 bia[2][4];
#pragma unroll
    for (int i = 0; i < 2; ++i)
#pragma unroll
      for (int j = 0; j < 4; ++j)
        bia[i][j] = *(const floatx4*)(b2p + (size_t)(tq + j*16 + lane15)*64 + c*32 + i*16 + quad*4);
    short8 af[2];
#pragma unroll
    for (int i = 0; i < 2; ++i)
      af[i] = *(const short8*)(ANC + quad*512 + (c*32 + i*16 + lane15)*8);
#pragma unroll
    for (int i = 0; i < 2; ++i)
#pragma unroll
      for (int j = 0; j < 4; ++j){
        floatx4 sv = __builtin_amdgcn_mfma_f32_16x16x32_bf16(af[i], qf2[j], zf4, 0, 0, 0);
        float p0 = exp2f(fmaf(sv[0], scale2, bia[i][j][0]));
        float p1 = exp2f(fmaf(sv[1], scale2, bia[i][j][1]));
        float p2 = exp2f(fmaf(sv[2], scale2, bia[i][j][2]));
        float p3 = exp2f(fmaf(sv[3], scale2, bia[i][j][3]));
        l2[j] += (p0 + p1) + (p2 + p3);
        uintx2 w; w.x = pk2(p0, p1); w.y = pk2(p2, p3);
        *(uintx2*)(P2T + (i*2 + (quad>>1))*512 + (j*16 + lane15)*8 + (quad&1)*4) = w;
      }
    asm volatile("s_waitcnt lgkmcnt(0)" ::: "memory");
    short8 ptf[4], xmf[2];
#pragma unroll
    for (int j = 0; j < 4; ++j)
      ptf[j] = *(const short8*)(P2T + quad*512 + (j*16 + lane15)*8);
#pragma unroll
    for (int m = 0; m < 2; ++m)
      xmf[m] = *(const short8*)(XMT + (c*4 + quad)*256 + (m*16 + lane15)*8);
#pragma unroll
    for (int m = 0; m < 2; ++m)
#pragma unroll
      for (int j = 0; j < 4; ++j)
        accO2[m][j] = __builtin_amdgcn_mfma_f32_16x16x32_bf16(xmf[m], ptf[j], accO2[m][j], 0, 0, 0);
  }
  float linv[4];
#pragma unroll
  for (int j = 0; j < 4; ++j) linv[j] = 1.f / redq(l2[j]);
#pragma unroll
  for (int m = 0; m < 2; ++m)
#pragma unroll
    for (int j = 0; j < 4; ++j){
      int tok = tq + j*16 + lane15;
      int py = r0 + syl*32 + (tok >> 5), px = sx*32 + (tok & 31);
      floatx4 o = accO2[m][j] * linv[j];
      *(floatx4*)(outm + (size_t)(py*256 + px)*256 + 128 + h*32 + m*16 + quad*4) = o;
    }
}

// ---------------- launch ----------------
extern "C" void kernel_launch(void* const* d_in, const int* in_sizes, int n_in,
                              void* d_out, int out_size, void* d_ws, size_t ws_size,
                              hipStream_t stream) {
  (void)in_sizes; (void)n_in; (void)out_size; (void)ws_size;
  const float* x        = (const float*)d_in[0];
  const float* qkv_w    = (const float*)d_in[1];
  const float* qkv_b    = (const float*)d_in[2];
  const float* anchor_w = (const float*)d_in[3];
  const float* anchor_b = (const float*)d_in[4];
  const float* ls_w     = (const float*)d_in[5];
  const float* w1_w     = (const float*)d_in[6];
  const float* b1_w     = (const float*)d_in[7];
  const float* w2_w     = (const float*)d_in[8];
  const float* ls_s1    = (const float*)d_in[9];
  const float* w1_s1    = (const float*)d_in[10];
  const float* b1_s1    = (const float*)d_in[11];
  const float* w2_s1    = (const float*)d_in[12];
  const float* ls_s2    = (const float*)d_in[13];
  const float* w1_s2    = (const float*)d_in[14];
  const float* b1_s2    = (const float*)d_in[15];
  const float* w2_s2    = (const float*)d_in[16];
  const float* proj_w   = (const float*)d_in[17];
  const float* proj_b   = (const float*)d_in[18];
  const float* table_w  = (const float*)d_in[19];
  const float* table_s  = (const float*)d_in[20];
  const int* index_w   = (const int*)d_in[21];
  const int* index_a2w = (const int*)d_in[22];
  const int* index_w2a = (const int*)d_in[23];

  // ---- workspace layout (31.1 MB peak) ----
  char* ws = (char*)d_ws;
  u16*   qkvh   = (u16*)(ws + 0);                  // 32768*256 bf16 = 16777216 B (normalized Q|K, reused 4x)
  float* pooled = (float*)(ws + 0);                // 4 MB; dead before qkvh written
  u16*   vt     = (u16*)(ws + 16777216);           // 128*32768 bf16 = 8388608 B (V^T, reused 4x)
  u16*   anch   = (u16*)(ws + 25165824);           // 4096*128 bf16 (normalized anchors)
  u16*   qkvt   = (u16*)(ws + 26214400);           // 768*256 bf16
  u16*   anct   = (u16*)(ws + 26607616);           // 128*256 bf16
  u16*   projt  = (u16*)(ws + 26673152);           // 256*256 bf16
  float* btw    = (float*)(ws + 26804224);
  float* bts1   = (float*)(ws + 26820608);
  float* bts2   = (float*)(ws + 26845184);
  float* biasw  = (float*)(ws + 26869760);         // 4*256*256 f32
  float* bias1  = (float*)(ws + 27918336);         // 4*64*1024 f32
  float* bias2  = (float*)(ws + 28966912);         // 4*1024*64 f32
  float* gl1    = (float*)(ws + 30015488);         // 256*64 f32
  u16*   gO     = (u16*)(ws + 30081024);           // 256*2048 bf16 (end 31129600)

  float* merged = (float*)d_out;                   // f32 scratch, then final output (in-place proj)

  transpose_w<<<1152, 256, 0, stream>>>(qkv_w, anchor_w, proj_w, qkvt, anct, projt);
  cpb_mlp<<<dim3(24, 3), 256, 0, stream>>>(table_w, table_s,
                                           w1_w, b1_w, w2_w,
                                           w1_s1, b1_s1, w2_s1,
                                           w1_s2, b1_s2, w2_s2,
                                           btw, bts1, bts2);
  bias_gather<<<3072, 256, 0, stream>>>(btw, bts1, bts2, index_w, index_a2w, index_w2a,
                                        ls_w, ls_s1, ls_s2, biasw, bias1, bias2);
  avgpool<<<4096, 256, 0, stream>>>(x, pooled);
  // anchor projection GEMM (y=0 -> normalized path), N=128
  gemm_qkv<<<dim3(32, 1), 256, 0, stream>>>(pooled, anct, anchor_b, anch, vt, 128, 256);

  for (int half = 0; half < 2; ++half){
    const float* xh = x + (size_t)half*32768*256;
    int r0 = half*128;
    // window branch: y=0/1 -> normalized Q|K into qkvh; y=2 -> V^T into vt
    gemm_qkv<<<dim3(256, 3), 256, 0, stream>>>(xh, qkvt, qkv_b, qkvh, vt, 256, 256);
    win_attn<<<dim3(128, 4), 256, 0, stream>>>(qkvh, vt, ls_w, biasw, merged, r0);
    // stripe branch
    gemm_qkv<<<dim3(256, 3), 256, 0, stream>>>(xh, qkvt + 384*256, qkv_b + 384, qkvh, vt, 256, 256);
    stripe_xm<<<dim3(32, 4, 2), 256, 0, stream>>>(qkvh, vt, anch, ls_s1, bias1, gl1, gO, r0);
    stripe_xs<<<dim3(128, 4), 256, 0, stream>>>(qkvh, anch, ls_s2, bias2, gl1, gO, merged, r0);
  }

  // output projection, in place on f32 d_out
  gemm_proj_inplace<<<dim3(512), 256, 0, stream>>>(merged, projt, proj_b);
}

// Round 4
// 396.577 us; speedup vs baseline: 1.0676x; 1.0676x over previous
//
#include <hip/hip_runtime.h>
#include <cstdint>
#include <cstddef>

typedef unsigned short u16;
typedef __attribute__((ext_vector_type(8))) short short8;
typedef __attribute__((ext_vector_type(4))) float floatx4;
typedef __attribute__((ext_vector_type(2))) float floatx2;
typedef __attribute__((ext_vector_type(4))) unsigned int uintx4;
typedef __attribute__((ext_vector_type(2))) unsigned int uintx2;
typedef __attribute__((ext_vector_type(2))) __bf16 bf16x2;

#define LOG2E 1.44269504f

__device__ __forceinline__ float bf2f(u16 u){
  union { unsigned int i; float f; } v; v.i = ((unsigned int)u) << 16; return v.f;
}
__device__ __forceinline__ u16 f2bf(float f){
  union { __bf16 b; u16 u; } v; v.b = (__bf16)f; return v.u;
}
// packed f32x2 -> bf16x2 (v_cvt_pk_bf16_f32, RNE)
__device__ __forceinline__ unsigned int pk2(float a, float b){
  union { bf16x2 h; unsigned int u; } v;
  v.h = __builtin_convertvector((floatx2){a, b}, bf16x2);
  return v.u;
}
// async global->LDS, 16B per lane (dest = wave-uniform base + lane*16)
__device__ __forceinline__ void gload16(const void* g, void* l){
  __builtin_amdgcn_global_load_lds((const __attribute__((address_space(1))) unsigned int*)g,
                                   (__attribute__((address_space(3))) unsigned int*)l, 16, 0, 0);
}
// load 8 fp32 from g, convert to 8 bf16 packed in a uintx4
__device__ __forceinline__ uintx4 ld8f_bf(const float* g){
  floatx4 u0 = *(const floatx4*)g;
  floatx4 u1 = *(const floatx4*)(g + 4);
  uintx4 w;
  w.x = pk2(u0.x, u0.y); w.y = pk2(u0.z, u0.w);
  w.z = pk2(u1.x, u1.y); w.w = pk2(u1.z, u1.w);
  return w;
}
__device__ __forceinline__ float redq(float v){   // sum across quads (lanes ^16, ^32)
  v += __shfl_xor(v, 16); v += __shfl_xor(v, 32);
  return v;
}

// ---------------- prep kernels ----------------
__global__ void transpose_w(const float* __restrict__ qkv_w, const float* __restrict__ anchor_w,
                            const float* __restrict__ proj_w,
                            u16* __restrict__ qkvt, u16* __restrict__ anct, u16* __restrict__ projt){
  int id = blockIdx.x*256 + threadIdx.x;
  if (id < 196608){ int k = id / 768, n = id % 768; qkvt[n*256 + k] = f2bf(qkv_w[id]); }
  else if (id < 229376){ int r = id - 196608; int k = r / 128, n = r % 128; anct[n*256 + k] = f2bf(anchor_w[r]); }
  else { int r = id - 229376; int k = r >> 8, n = r & 255; projt[n*256 + k] = f2bf(proj_w[r]); }
}

__global__ void cpb_mlp(const float* __restrict__ tw, const float* __restrict__ ts,
                        const float* __restrict__ w1w, const float* __restrict__ b1w, const float* __restrict__ w2w,
                        const float* __restrict__ w1s1, const float* __restrict__ b1s1, const float* __restrict__ w2s1,
                        const float* __restrict__ w1s2, const float* __restrict__ b1s2, const float* __restrict__ w2s2,
                        float* __restrict__ btw, float* __restrict__ bts1, float* __restrict__ bts2){
  int tag = blockIdx.y;
  const float *tab, *w1, *b1, *w2; float* bt; int T;
  if (tag == 0){ tab = tw; w1 = w1w;  b1 = b1w;  w2 = w2w;  bt = btw;  T = 961; }
  else if (tag == 1){ tab = ts; w1 = w1s1; b1 = b1s1; w2 = w2s1; bt = bts1; T = 1521; }
  else { tab = ts; w1 = w1s2; b1 = b1s2; w2 = w2s2; bt = bts2; T = 1521; }
  __shared__ float sw1[2][512];
  __shared__ float sb1[512];
  __shared__ float sw2[512][4];
  for (int j = threadIdx.x; j < 512; j += 256){
    sw1[0][j] = w1[j]; sw1[1][j] = w1[512 + j]; sb1[j] = b1[j];
    for (int h = 0; h < 4; ++h) sw2[j][h] = w2[j*4 + h];
  }
  __syncthreads();
  int idx = blockIdx.x*256 + threadIdx.x;
  int r = idx >> 2, hh = idx & 3;
  if (r < T){
    float t0 = tab[2*r], t1 = tab[2*r + 1];
    float acc = 0.f;
    for (int j = 0; j < 512; ++j){
      float hj = fmaxf(fmaf(t0, sw1[0][j], fmaf(t1, sw1[1][j], sb1[j])), 0.f);
      acc = fmaf(hj, sw2[j][hh], acc);
    }
    bt[r*4 + hh] = acc;
  }
}

// bias tables pre-folded: (16*sigmoid(v) - off_h) * log2(e), off_h = min(scale_h+16, 80)
// AND re-laid-out so attention loads are query-contiguous floatx4 per key-quad:
//  biasw : idx = ((((h*8+kc)*2+i)*4+quad)*256 + q)*4 + r      (k = kc*32+i*16+quad*4+r, q=0..255)
//  bias1 : idx = (((h*64+kg)*4+quad)*64 + a)*4 + r            (k = kg*16+quad*4+r, a=0..63)
//  bias2 : idx = (((h*4+kg)*4+quad)*1024 + q)*4 + r           (k = kg*16+quad*4+r, q=0..1023)
__global__ void bias_gather(const float* __restrict__ btw, const float* __restrict__ bts1,
                            const float* __restrict__ bts2,
                            const int* __restrict__ idxw, const int* __restrict__ idxa2w,
                            const int* __restrict__ idxw2a,
                            const float* __restrict__ lsw, const float* __restrict__ ls1,
                            const float* __restrict__ ls2,
                            float* __restrict__ bw, float* __restrict__ bs1, float* __restrict__ bs2){
  int id = blockIdx.x*256 + threadIdx.x;     // 3 * 262144
  int which = id >> 18;
  int rem = id & 262143;
  int h = rem >> 16, e = rem & 65535;
  const float* bt; const int* ix; float* dst; const float* ls;
  if (which == 0){ bt = btw;  ix = idxw;   dst = bw;  ls = lsw; }
  else if (which == 1){ bt = bts1; ix = idxa2w; dst = bs1; ls = ls1; }
  else { bt = bts2; ix = idxw2a; dst = bs2; ls = ls2; }
  float v = bt[ix[e]*4 + h];
  float scale = exp2f(fminf(ls[h], 4.6051702f) * LOG2E);
  float off = fminf(scale + 16.f, 80.f);
  float sig = 16.f / (1.f + exp2f(-v * LOG2E));
  float out = (sig - off) * LOG2E;
  int idx;
  if (which == 0){
    int q = e >> 8, k = e & 255;
    idx = ((((h*8 + (k>>5))*2 + ((k>>4)&1))*4 + ((k>>2)&3)) << 10) + (q << 2) + (k & 3);
  } else if (which == 1){
    int a = e >> 10, k = e & 1023;
    idx = (((h*64 + (k>>4))*4 + ((k>>2)&3)) << 8) + (a << 2) + (k & 3);
  } else {
    int q = e >> 6, k = e & 63;
    idx = (((h*4 + (k>>4))*4 + ((k>>2)&3)) << 12) + (q << 2) + (k & 3);
  }
  dst[idx] = out;
}

__global__ void avgpool(const float* __restrict__ x, float* __restrict__ pooled){
  int a = blockIdx.x, c = threadIdx.x;
  int ay = a >> 6, ax = a & 63;
  float acc = 0.f;
#pragma unroll
  for (int dy = 0; dy < 4; ++dy)
#pragma unroll
    for (int dx = 0; dx < 4; ++dx)
      acc += x[(size_t)((ay*4 + dy)*256 + ax*4 + dx)*256 + c];
  pooled[(size_t)a*256 + c] = acc * 0.0625f;
}

// ---------------- GEMM: C[M, N](bf16) = norm?( A[M,K](f32) @ Bt^T + bias ) ----------------
// grid.y picks a 128-col slice of Bt/bias/C. y<2 -> per-(row, 32-col head) L2 normalize
// (Q/K/anchor); y==2 -> plain bias add (V). Swapped MFMA so acc r runs along columns.
__launch_bounds__(256, 2)
__global__ void gemm_qkv(const float* __restrict__ A, const u16* __restrict__ Bt,
                         const float* __restrict__ bias, u16* __restrict__ C,
                         int N, int K){
  __shared__ __align__(16) u16 lsA[4096];   // [4 kq][128 rows][8], +2-row skew per kq
  __shared__ __align__(16) u16 lsB[4096];   // [128 rows][32 k] linear (global_load_lds dest)
  const int tid = threadIdx.x, lane = tid & 63, wv = tid >> 6;
  const int lane15 = lane & 15, quad = lane >> 4;
  const int wr = wv >> 1, wc = wv & 1;
  const int m0 = blockIdx.x * 128;
  const int y = blockIdx.y;
  const u16* Btb = Bt + (size_t)y*128*K;
  const float* bb = bias + y*128;
  char* lsBb = (char*)lsB;
  const int brow = wv*16 + (lane >> 2);
  const u16* bsrc = Btb + (size_t)brow*K + (lane & 3)*8;
  const int arow = tid & 127, aq = tid >> 7;          // this thread stages kq = aq and aq+2
  const float* asrc = A + (size_t)(m0 + arow)*K;
  const int aslot0 = aq*1024 + ((arow + aq*2) & 127)*8;
  const int aslot1 = (aq+2)*1024 + ((arow + (aq+2)*2) & 127)*8;
  floatx4 acc[4][4] = {};
  for (int k0 = 0; k0 < K; k0 += 32){
    gload16(bsrc + k0,                 lsBb + wv*1024);          // rows 0..63
    gload16(bsrc + (size_t)64*K + k0,  lsBb + 4096 + wv*1024);   // rows 64..127
    uintx4 ra0 = ld8f_bf(asrc + k0 + aq*8);
    uintx4 ra1 = ld8f_bf(asrc + k0 + (aq+2)*8);
    *(uintx4*)(lsA + aslot0) = ra0;
    *(uintx4*)(lsA + aslot1) = ra1;
    __syncthreads();
    short8 a[4], b[4];
#pragma unroll
    for (int i = 0; i < 4; ++i){
      int r = wr*64 + i*16 + lane15;
      a[i] = *(const short8*)(lsA + quad*1024 + ((r + quad*2) & 127)*8);
    }
#pragma unroll
    for (int j = 0; j < 4; ++j)
      b[j] = *(const short8*)(lsBb + (wc*64 + j*16 + lane15)*64 + quad*16);
#pragma unroll
    for (int i = 0; i < 4; ++i)
#pragma unroll
      for (int j = 0; j < 4; ++j)
        acc[i][j] = __builtin_amdgcn_mfma_f32_16x16x32_bf16(b[j], a[i], acc[i][j], 0, 0, 0);
    __syncthreads();
  }
  // swapped mapping: lane15 -> row(m), quad*4+r -> col(n within 128-slice)
#pragma unroll
  for (int j = 0; j < 4; ++j){
    floatx4 bz = *(const floatx4*)(bb + wc*64 + j*16 + quad*4);
#pragma unroll
    for (int i = 0; i < 4; ++i) acc[i][j] += bz;
  }
  if (y < 2){
    // per-(row, 32-col head) L2 normalization: head = j-pair; sum r + quads
#pragma unroll
    for (int i = 0; i < 4; ++i){
#pragma unroll
      for (int jp = 0; jp < 2; ++jp){
        floatx4 s2 = acc[i][jp*2]*acc[i][jp*2] + acc[i][jp*2+1]*acc[i][jp*2+1];
        float ss = (s2.x + s2.y) + (s2.z + s2.w);
        ss = redq(ss);
        float inv = 1.f / fmaxf(sqrtf(ss), 1e-12f);
        acc[i][jp*2]   *= inv;
        acc[i][jp*2+1] *= inv;
      }
    }
  }
#pragma unroll
  for (int i = 0; i < 4; ++i){
    int row = m0 + wr*64 + i*16 + lane15;
#pragma unroll
    for (int j = 0; j < 4; ++j){
      int colb = y*128 + wc*64 + j*16 + quad*4;
      uintx2 w;
      w.x = pk2(acc[i][j][0], acc[i][j][1]);
      w.y = pk2(acc[i][j][2], acc[i][j][3]);
      *(uintx2*)(C + (size_t)row*N + colb) = w;
    }
  }
}

// ---------------- in-place proj GEMM: AC[M,256](f32) <- AC @ Bt^T + bias ----------------
__launch_bounds__(256, 2)
__global__ void gemm_proj_inplace(float* __restrict__ AC, const u16* __restrict__ Bt,
                                  const float* __restrict__ bias){
  __shared__ __align__(16) u16 lsA[4096];   // [4 kq][128][8], skewed
  __shared__ __align__(16) u16 lsB[8192];   // [256 rows][32 k] linear
  const int tid = threadIdx.x, lane = tid & 63, wv = tid >> 6;
  const int lane15 = lane & 15, quad = lane >> 4;
  const int wr = wv >> 1, wc = wv & 1;     // wave = 64 rows x 128 cols
  const int m0 = blockIdx.x * 128;
  char* lsBb = (char*)lsB;
  const int brow = wv*16 + (lane >> 2);
  const u16* bsrc = Bt + (size_t)brow*256 + (lane & 3)*8;
  const int arow = tid & 127, aq = tid >> 7;
  const float* asrc = AC + (size_t)(m0 + arow)*256;
  const int aslot0 = aq*1024 + ((arow + aq*2) & 127)*8;
  const int aslot1 = (aq+2)*1024 + ((arow + (aq+2)*2) & 127)*8;
  floatx4 acc[4][8] = {};
  for (int k0 = 0; k0 < 256; k0 += 32){
    gload16(bsrc + k0,                lsBb +         wv*1024);
    gload16(bsrc + 64*256 + k0,       lsBb + 4096  + wv*1024);
    gload16(bsrc + 128*256 + k0,      lsBb + 8192  + wv*1024);
    gload16(bsrc + 192*256 + k0,      lsBb + 12288 + wv*1024);
    uintx4 ra0 = ld8f_bf(asrc + k0 + aq*8);
    uintx4 ra1 = ld8f_bf(asrc + k0 + (aq+2)*8);
    *(uintx4*)(lsA + aslot0) = ra0;
    *(uintx4*)(lsA + aslot1) = ra1;
    __syncthreads();
    short8 a[4], b[8];
#pragma unroll
    for (int i = 0; i < 4; ++i){
      int r = wr*64 + i*16 + lane15;
      a[i] = *(const short8*)(lsA + quad*1024 + ((r + quad*2) & 127)*8);
    }
#pragma unroll
    for (int j = 0; j < 8; ++j)
      b[j] = *(const short8*)(lsBb + (wc*128 + j*16 + lane15)*64 + quad*16);
#pragma unroll
    for (int i = 0; i < 4; ++i)
#pragma unroll
      for (int j = 0; j < 8; ++j)
        acc[i][j] = __builtin_amdgcn_mfma_f32_16x16x32_bf16(b[j], a[i], acc[i][j], 0, 0, 0);
    __syncthreads();
  }
#pragma unroll
  for (int i = 0; i < 4; ++i){
    int row = m0 + wr*64 + i*16 + lane15;
#pragma unroll
    for (int j = 0; j < 8; ++j){
      int colb = wc*128 + j*16 + quad*4;
      floatx4 bz = *(const floatx4*)(bias + colb);
      floatx4 o = acc[i][j] + bz;
      *(floatx4*)(AC + (size_t)row*256 + colb) = o;
    }
  }
}

// ---------------- window attention (S^T formulation) ----------------
// qkvh: [32768][384] bf16, Qn[0,128) Kn[128,256) V[256,384); grid (128 windows, 4 heads)
__launch_bounds__(256, 3)
__global__ void win_attn(const u16* __restrict__ qkvh, const float* __restrict__ lsw,
                         const float* __restrict__ biasw, float* __restrict__ outm, int r0){
  __shared__ __align__(16) u16 sm[24576];   // 48 KB: K[0,8192) Q[8192,16384)->P  VT[16384,24576)
  const int tid = threadIdx.x, lane = tid & 63, wv = tid >> 6;
  const int lane15 = lane & 15, quad = lane >> 4;
  const int h = blockIdx.y;
  const int wyl = blockIdx.x >> 4, wx = blockIdx.x & 15;
  u16* Ks = sm;
  u16* Qs = sm + 8192;
  u16* VT = sm + 16384;
  { // stage: DMA Q,K (pre-normalized) into k-outer [kq][256 tok][8]; V scalar-transposed
    int tok = wv*64 + lane;
    int row = (wyl*16 + (tok >> 4))*256 + wx*16 + (tok & 15);
    const char* src = (const char*)qkvh + (size_t)row*768 + h*64;
#pragma unroll
    for (int kq = 0; kq < 4; ++kq){
      gload16(src + kq*16,        (char*)Qs + wv*1024 + kq*4096);
      gload16(src + 256 + kq*16,  (char*)Ks + wv*1024 + kq*4096);
    }
    // V: this thread's token = tid; direct u16 transpose into VT[oct][32 d][8]
    int vrow = (wyl*16 + (tid >> 4))*256 + wx*16 + (tid & 15);
    const uintx4* vp = (const uintx4*)((const char*)qkvh + (size_t)vrow*768 + 512 + h*64);
    uintx4 v0 = vp[0], v1 = vp[1], v2 = vp[2], v3 = vp[3];
    unsigned int w[16] = {v0.x,v0.y,v0.z,v0.w, v1.x,v1.y,v1.z,v1.w,
                          v2.x,v2.y,v2.z,v2.w, v3.x,v3.y,v3.z,v3.w};
    u16* vd = VT + (tid >> 3)*256 + (tid & 7);
#pragma unroll
    for (int c = 0; c < 16; ++c){
      vd[(c*2)*8]   = (u16)(w[c] & 0xffffu);
      vd[(c*2+1)*8] = (u16)(w[c] >> 16);
    }
  }
  __syncthreads();
  short8 qf[4];                 // wave owns queries wv*64 .. +63 (B-operand)
#pragma unroll
  for (int j = 0; j < 4; ++j)
    qf[j] = *(const short8*)(Qs + quad*2048 + (wv*64 + j*16 + lane15)*8);
  __syncthreads();              // all Q reads done before P overwrites

  float scale = exp2f(fminf(lsw[h], 4.6051702f) * LOG2E) * LOG2E;
  u16* Pw = Qs + wv*2048;       // per-wave P^T: [4 key-octs][64 queries][8]
  const floatx4 zf4 = {0.f, 0.f, 0.f, 0.f};
  floatx4 accO[2][4] = {};      // O^T: [d-tile][query-tile]
  float lsum[4] = {};

  for (int kc = 0; kc < 8; ++kc){      // 32 keys per chunk
    floatx4 bia[2][4];
#pragma unroll
    for (int i = 0; i < 2; ++i)
#pragma unroll
      for (int j = 0; j < 4; ++j)
        bia[i][j] = *(const floatx4*)(biasw + ((((h*8 + kc)*2 + i)*4 + quad) << 10)
                                            + ((wv*64 + j*16 + lane15) << 2));
    short8 kf[2];
#pragma unroll
    for (int i = 0; i < 2; ++i)
      kf[i] = *(const short8*)(Ks + quad*2048 + (kc*32 + i*16 + lane15)*8);
#pragma unroll
    for (int i = 0; i < 2; ++i)
#pragma unroll
      for (int j = 0; j < 4; ++j){
        floatx4 sv = __builtin_amdgcn_mfma_f32_16x16x32_bf16(kf[i], qf[j], zf4, 0, 0, 0);
        float p0 = exp2f(fmaf(sv[0], scale, bia[i][j][0]));
        float p1 = exp2f(fmaf(sv[1], scale, bia[i][j][1]));
        float p2 = exp2f(fmaf(sv[2], scale, bia[i][j][2]));
        float p3 = exp2f(fmaf(sv[3], scale, bia[i][j][3]));
        lsum[j] += (p0 + p1) + (p2 + p3);
        uintx2 w; w.x = pk2(p0, p1); w.y = pk2(p2, p3);
        *(uintx2*)(Pw + (i*2 + (quad>>1))*512 + (j*16 + lane15)*8 + (quad&1)*4) = w;
      }
    asm volatile("s_waitcnt lgkmcnt(0)" ::: "memory");
    short8 ptf[4], vtf[2];
#pragma unroll
    for (int j = 0; j < 4; ++j)
      ptf[j] = *(const short8*)(Pw + quad*512 + (j*16 + lane15)*8);
#pragma unroll
    for (int m = 0; m < 2; ++m)
      vtf[m] = *(const short8*)(VT + (kc*4 + quad)*256 + (m*16 + lane15)*8);
#pragma unroll
    for (int m = 0; m < 2; ++m)
#pragma unroll
      for (int j = 0; j < 4; ++j)
        accO[m][j] = __builtin_amdgcn_mfma_f32_16x16x32_bf16(vtf[m], ptf[j], accO[m][j], 0, 0, 0);
  }
  float linv[4];
#pragma unroll
  for (int j = 0; j < 4; ++j) linv[j] = 1.f / redq(lsum[j]);
#pragma unroll
  for (int m = 0; m < 2; ++m)
#pragma unroll
    for (int j = 0; j < 4; ++j){
      int tok = wv*64 + j*16 + lane15;
      int py = r0 + wyl*16 + (tok >> 4), px = wx*16 + (tok & 15);
      floatx4 o = accO[m][j] * linv[j];
      *(floatx4*)(outm + (size_t)(py*256 + px)*256 + h*32 + m*16 + quad*4) = o;
    }
}

// ---------------- stripe phase 1: xm partials (key-split) ----------------
// grid (32 stripes, 4 heads, 2 key-halves)
__launch_bounds__(256, 3)
__global__ void stripe_xm(const u16* __restrict__ qkvh, const u16* __restrict__ anchor,
                          const float* __restrict__ ls1, const float* __restrict__ bias1,
                          float* __restrict__ gl1, u16* __restrict__ gO, int r0){
  __shared__ __align__(16) u16 sm[22528];  // 44KB: ANC[0,2048) KC0[2048,6144) KC1[6144,10240) VT[10240,14336) P1T[14336,22528)
  const int tid = threadIdx.x, lane = tid & 63, wv = tid >> 6;
  const int lane15 = lane & 15, quad = lane >> 4;
  const int s = blockIdx.x, h = blockIdx.y, kb = blockIdx.z;
  const int syl = s >> 3, sx = s & 7;
  u16* ANC = sm; u16* VT = sm + 10240; u16* P1T = sm + 14336;
  if (wv == 0){   // anchors pre-normalized in anch
    int ay = (r0 >> 2) + syl*8 + (lane >> 3), ax = sx*8 + (lane & 7);
    const char* asrc = (const char*)anchor + (size_t)(ay*64 + ax)*256 + h*64;
#pragma unroll
    for (int kq = 0; kq < 4; ++kq)
      gload16(asrc + kq*16, (char*)ANC + kq*1024);
  }
  // K chunk staging via DMA: wave wv stages kq=wv for 128 tokens (2 gloads)
  auto stageK = [&](int kc){
    int kkb = kb*512 + kc*128;
    char* KC = (char*)sm + 4096 + (kc & 1)*8192;
#pragma unroll
    for (int hf = 0; hf < 2; ++hf){
      int tok = kkb + hf*64 + lane;
      int row = (syl*32 + (tok >> 5))*256 + sx*32 + (tok & 31);
      gload16((const char*)qkvh + (size_t)row*768 + 256 + h*64 + wv*16,
              KC + wv*2048 + hf*1024);
    }
  };
  stageK(0);
  float scale1 = exp2f(fminf(ls1[h], 4.6051702f) * LOG2E) * LOG2E;
  const floatx4 zf4 = {0.f, 0.f, 0.f, 0.f};
  floatx4 accO1[2] = {};
  float l1 = 0.f;
  for (int kc = 0; kc < 4; ++kc){
    int kkb = kb*512 + kc*128;
    { // stage V(kc): thread -> token tid>>1, d-half tid&1; direct u16 transpose
      int tok_l = tid >> 1, dh = tid & 1;
      int tok = kkb + tok_l;
      int row = (syl*32 + (tok >> 5))*256 + sx*32 + (tok & 31);
      const uintx4* vp = (const uintx4*)((const char*)qkvh + (size_t)row*768 + 512 + h*64 + dh*32);
      uintx4 v0 = vp[0], v1 = vp[1];
      unsigned int w[8] = {v0.x,v0.y,v0.z,v0.w, v1.x,v1.y,v1.z,v1.w};
      u16* vd = VT + (tok_l >> 3)*256 + dh*128 + (tok_l & 7);
#pragma unroll
      for (int c = 0; c < 8; ++c){
        vd[(c*2)*8]   = (u16)(w[c] & 0xffffu);
        vd[(c*2+1)*8] = (u16)(w[c] >> 16);
      }
    }
    __syncthreads();                       // VT visible; KC(kc) DMA drained; ANC ready
    if (kc < 3) stageK(kc + 1);            // overlaps QK+PV compute, drains at end barrier
    const u16* KC = sm + 2048 + (kc & 1)*4096;
    short8 ancf = *(const short8*)(ANC + quad*512 + (wv*16 + lane15)*8);
    floatx4 bia[8];
#pragma unroll
    for (int i = 0; i < 8; ++i)
      bia[i] = *(const floatx4*)(bias1 + (((h*64 + kb*32 + kc*8 + i)*4 + quad) << 8)
                                       + ((wv*16 + lane15) << 2));
#pragma unroll
    for (int i = 0; i < 8; ++i){
      short8 kf = *(const short8*)(KC + quad*1024 + (i*16 + lane15)*8);
      floatx4 sv = __builtin_amdgcn_mfma_f32_16x16x32_bf16(kf, ancf, zf4, 0, 0, 0);
      float p0 = exp2f(fmaf(sv[0], scale1, bia[i][0]));
      float p1 = exp2f(fmaf(sv[1], scale1, bia[i][1]));
      float p2 = exp2f(fmaf(sv[2], scale1, bia[i][2]));
      float p3 = exp2f(fmaf(sv[3], scale1, bia[i][3]));
      l1 += (p0 + p1) + (p2 + p3);
      uintx2 w; w.x = pk2(p0, p1); w.y = pk2(p2, p3);
      *(uintx2*)(P1T + (i*2 + (quad>>1))*512 + (wv*16 + lane15)*8 + (quad&1)*4) = w;
    }
    asm volatile("s_waitcnt lgkmcnt(0)" ::: "memory");
#pragma unroll
    for (int ks = 0; ks < 4; ++ks){
      short8 ptf = *(const short8*)(P1T + (ks*4 + quad)*512 + (wv*16 + lane15)*8);
#pragma unroll
      for (int m = 0; m < 2; ++m){
        short8 vtf = *(const short8*)(VT + (ks*4 + quad)*256 + (m*16 + lane15)*8);
        accO1[m] = __builtin_amdgcn_mfma_f32_16x16x32_bf16(vtf, ptf, accO1[m], 0, 0, 0);
      }
    }
    __syncthreads();   // protect VT/P1T before next-iter staging
  }
  l1 = redq(l1);
  int ent = (s*4 + h)*2 + kb;
  if (quad == 0) gl1[ent*64 + wv*16 + lane15] = l1;
#pragma unroll
  for (int m = 0; m < 2; ++m){
    uintx2 w; w.x = pk2(accO1[m][0], accO1[m][1]); w.y = pk2(accO1[m][2], accO1[m][3]);
    *(uintx2*)(gO + (size_t)ent*2048 + (wv*16 + lane15)*32 + m*16 + quad*4) = w;
  }
}

// ---------------- stripe phase 2: xs ----------------
// grid (32 stripes * 4 query-chunks, 4 heads)
__launch_bounds__(256, 3)
__global__ void stripe_xs(const u16* __restrict__ qkvh, const u16* __restrict__ anchor,
                          const float* __restrict__ ls2, const float* __restrict__ bias2,
                          const float* __restrict__ gl1, const u16* __restrict__ gO,
                          float* __restrict__ outm, int r0){
  __shared__ __align__(16) u16 sm[20480]; // ANC[0,2048) XMT[2048,4096) QW[4096+wv*2048) P2T[12288+wv*2048)
  const int tid = threadIdx.x, lane = tid & 63, wv = tid >> 6;
  const int lane15 = lane & 15, quad = lane >> 4;
  const int s = blockIdx.x >> 2, qc = blockIdx.x & 3, h = blockIdx.y;
  const int syl = s >> 3, sx = s & 7;
  u16* ANC = sm;
  u16* XMT = sm + 2048;
  u16* QW  = sm + 4096 + wv*2048;
  u16* P2T = sm + 12288 + wv*2048;
  if (wv == 0){
    int ay = (r0 >> 2) + syl*8 + (lane >> 3), ax = sx*8 + (lane & 7);
    const char* asrc = (const char*)anchor + (size_t)(ay*64 + ax)*256 + h*64;
#pragma unroll
    for (int kq = 0; kq < 4; ++kq)
      gload16(asrc + kq*16, (char*)ANC + kq*1024);
  }
  { // combine xm partials -> XMT [anchor-oct][d 32][8] bf16
    int a = tid >> 2, db = (tid & 3)*8;
    int e0 = (s*4 + h)*2;
    float inv = 1.f / (gl1[e0*64 + a] + gl1[(e0 + 1)*64 + a]);
    uintx4 u0 = *(const uintx4*)(gO + (size_t)e0*2048 + a*32 + db);
    uintx4 u1 = *(const uintx4*)(gO + (size_t)(e0 + 1)*2048 + a*32 + db);
    unsigned int w0[4] = {u0.x, u0.y, u0.z, u0.w};
    unsigned int w1[4] = {u1.x, u1.y, u1.z, u1.w};
#pragma unroll
    for (int c = 0; c < 4; ++c){
      float a0 = bf2f((u16)(w0[c] & 0xffffu)) + bf2f((u16)(w1[c] & 0xffffu));
      float a1 = bf2f((u16)(w0[c] >> 16))     + bf2f((u16)(w1[c] >> 16));
      XMT[(a >> 3)*256 + (db + c*2)*8     + (a & 7)] = f2bf(a0 * inv);
      XMT[(a >> 3)*256 + (db + c*2 + 1)*8 + (a & 7)] = f2bf(a1 * inv);
    }
  }
  int tq = qc*256 + wv*64;     // query base within stripe (wave owns 64)
  { // DMA stage this wave's 64 queries (pre-normalized)
    int tok = tq + lane;
    int row = (syl*32 + (tok >> 5))*256 + sx*32 + (tok & 31);
    const char* src = (const char*)qkvh + (size_t)row*768 + h*64;
#pragma unroll
    for (int kq = 0; kq < 4; ++kq)
      gload16(src + kq*16, (char*)QW + kq*1024);
  }
  __syncthreads();
  short8 qf2[4];
#pragma unroll
  for (int j = 0; j < 4; ++j)
    qf2[j] = *(const short8*)(QW + quad*512 + (j*16 + lane15)*8);
  float scale2 = exp2f(fminf(ls2[h], 4.6051702f) * LOG2E) * LOG2E;
  const floatx4 zf4 = {0.f, 0.f, 0.f, 0.f};
  floatx4 accO2[2][4] = {};
  float l2[4] = {};
#pragma unroll
  for (int c = 0; c < 2; ++c){      // 2 anchor chunks of 32
    floatx4 bia[2][4];
#pragma unroll
    for (int i = 0; i < 2; ++i)
#pragma unroll
      for (int j = 0; j < 4; ++j)
        bia[i][j] = *(const floatx4*)(bias2 + ((((h*4 + c*2 + i)*4 + quad) << 12)
                                             + ((tq + j*16 + lane15) << 2)));
    short8 af[2];
#pragma unroll
    for (int i = 0; i < 2; ++i)
      af[i] = *(const short8*)(ANC + quad*512 + (c*32 + i*16 + lane15)*8);
#pragma unroll
    for (int i = 0; i < 2; ++i)
#pragma unroll
      for (int j = 0; j < 4; ++j){
        floatx4 sv = __builtin_amdgcn_mfma_f32_16x16x32_bf16(af[i], qf2[j], zf4, 0, 0, 0);
        float p0 = exp2f(fmaf(sv[0], scale2, bia[i][j][0]));
        float p1 = exp2f(fmaf(sv[1], scale2, bia[i][j][1]));
        float p2 = exp2f(fmaf(sv[2], scale2, bia[i][j][2]));
        float p3 = exp2f(fmaf(sv[3], scale2, bia[i][j][3]));
        l2[j] += (p0 + p1) + (p2 + p3);
        uintx2 w; w.x = pk2(p0, p1); w.y = pk2(p2, p3);
        *(uintx2*)(P2T + (i*2 + (quad>>1))*512 + (j*16 + lane15)*8 + (quad&1)*4) = w;
      }
    asm volatile("s_waitcnt lgkmcnt(0)" ::: "memory");
    short8 ptf[4], xmf[2];
#pragma unroll
    for (int j = 0; j < 4; ++j)
      ptf[j] = *(const short8*)(P2T + quad*512 + (j*16 + lane15)*8);
#pragma unroll
    for (int m = 0; m < 2; ++m)
      xmf[m] = *(const short8*)(XMT + (c*4 + quad)*256 + (m*16 + lane15)*8);
#pragma unroll
    for (int m = 0; m < 2; ++m)
#pragma unroll
      for (int j = 0; j < 4; ++j)
        accO2[m][j] = __builtin_amdgcn_mfma_f32_16x16x32_bf16(xmf[m], ptf[j], accO2[m][j], 0, 0, 0);
  }
  float linv[4];
#pragma unroll
  for (int j = 0; j < 4; ++j) linv[j] = 1.f / redq(l2[j]);
#pragma unroll
  for (int m = 0; m < 2; ++m)
#pragma unroll
    for (int j = 0; j < 4; ++j){
      int tok = tq + j*16 + lane15;
      int py = r0 + syl*32 + (tok >> 5), px = sx*32 + (tok & 31);
      floatx4 o = accO2[m][j] * linv[j];
      *(floatx4*)(outm + (size_t)(py*256 + px)*256 + 128 + h*32 + m*16 + quad*4) = o;
    }
}

// ---------------- launch ----------------
extern "C" void kernel_launch(void* const* d_in, const int* in_sizes, int n_in,
                              void* d_out, int out_size, void* d_ws, size_t ws_size,
                              hipStream_t stream) {
  (void)in_sizes; (void)n_in; (void)out_size; (void)ws_size;
  const float* x        = (const float*)d_in[0];
  const float* qkv_w    = (const float*)d_in[1];
  const float* qkv_b    = (const float*)d_in[2];
  const float* anchor_w = (const float*)d_in[3];
  const float* anchor_b = (const float*)d_in[4];
  const float* ls_w     = (const float*)d_in[5];
  const float* w1_w     = (const float*)d_in[6];
  const float* b1_w     = (const float*)d_in[7];
  const float* w2_w     = (const float*)d_in[8];
  const float* ls_s1    = (const float*)d_in[9];
  const float* w1_s1    = (const float*)d_in[10];
  const float* b1_s1    = (const float*)d_in[11];
  const float* w2_s1    = (const float*)d_in[12];
  const float* ls_s2    = (const float*)d_in[13];
  const float* w1_s2    = (const float*)d_in[14];
  const float* b1_s2    = (const float*)d_in[15];
  const float* w2_s2    = (const float*)d_in[16];
  const float* proj_w   = (const float*)d_in[17];
  const float* proj_b   = (const float*)d_in[18];
  const float* table_w  = (const float*)d_in[19];
  const float* table_s  = (const float*)d_in[20];
  const int* index_w   = (const int*)d_in[21];
  const int* index_a2w = (const int*)d_in[22];
  const int* index_w2a = (const int*)d_in[23];

  // ---- workspace layout (31.1 MB peak) ----
  char* ws = (char*)d_ws;
  u16*   qkvh   = (u16*)(ws + 0);                  // 32768*384 bf16 = 25165824 B (Qn|Kn|V, reused 4x)
  float* pooled = (float*)(ws + 0);                // 4096*256 f32 = 4 MB; dead before qkvh written
  u16*   anch   = (u16*)(ws + 25165824);           // 4096*128 bf16 (normalized anchors)
  u16*   qkvt   = (u16*)(ws + 26214400);           // 768*256 bf16
  u16*   anct   = (u16*)(ws + 26607616);           // 128*256 bf16
  u16*   projt  = (u16*)(ws + 26673152);           // 256*256 bf16
  float* btw    = (float*)(ws + 26804224);
  float* bts1   = (float*)(ws + 26820608);
  float* bts2   = (float*)(ws + 26845184);
  float* biasw  = (float*)(ws + 26869760);         // 4*256*256 f32
  float* bias1  = (float*)(ws + 27918336);         // 4*64*1024 f32
  float* bias2  = (float*)(ws + 28966912);         // 4*1024*64 f32
  float* gl1    = (float*)(ws + 30015488);         // 256*64 f32
  u16*   gO     = (u16*)(ws + 30081024);           // 256*2048 bf16 (end 31129600)

  float* merged = (float*)d_out;                   // f32 scratch, then final output (in-place proj)

  transpose_w<<<1152, 256, 0, stream>>>(qkv_w, anchor_w, proj_w, qkvt, anct, projt);
  cpb_mlp<<<dim3(24, 3), 256, 0, stream>>>(table_w, table_s,
                                           w1_w, b1_w, w2_w,
                                           w1_s1, b1_s1, w2_s1,
                                           w1_s2, b1_s2, w2_s2,
                                           btw, bts1, bts2);
  bias_gather<<<3072, 256, 0, stream>>>(btw, bts1, bts2, index_w, index_a2w, index_w2a,
                                        ls_w, ls_s1, ls_s2, biasw, bias1, bias2);
  avgpool<<<4096, 256, 0, stream>>>(x, pooled);
  // anchor projection GEMM, grid.y=1 -> y=0 normalized path, N=128
  gemm_qkv<<<dim3(32, 1), 256, 0, stream>>>(pooled, anct, anchor_b, anch, 128, 256);

  for (int half = 0; half < 2; ++half){
    const float* xh = x + (size_t)half*32768*256;
    int r0 = half*128;
    // window branch, qkv channels [0,384): y=0 Qn, y=1 Kn, y=2 V
    gemm_qkv<<<dim3(256, 3), 256, 0, stream>>>(xh, qkvt, qkv_b, qkvh, 384, 256);
    win_attn<<<dim3(128, 4), 256, 0, stream>>>(qkvh, ls_w, biasw, merged, r0);
    // stripe branch, qkv channels [384,768)
    gemm_qkv<<<dim3(256, 3), 256, 0, stream>>>(xh, qkvt + 384*256, qkv_b + 384, qkvh, 384, 256);
    stripe_xm<<<dim3(32, 4, 2), 256, 0, stream>>>(qkvh, anch, ls_s1, bias1, gl1, gO, r0);
    stripe_xs<<<dim3(128, 4), 256, 0, stream>>>(qkvh, anch, ls_s2, bias2, gl1, gO, merged, r0);
  }

  // output projection, in place on f32 d_out
  gemm_proj_inplace<<<dim3(512), 256, 0, stream>>>(merged, projt, proj_b);
}

// Round 5
// 351.190 us; speedup vs baseline: 1.2056x; 1.1292x over previous
//
#include <hip/hip_runtime.h>
#include <cstdint>
#include <cstddef>

typedef unsigned short u16;
typedef __attribute__((ext_vector_type(8))) short short8;
typedef __attribute__((ext_vector_type(4))) float floatx4;
typedef __attribute__((ext_vector_type(2))) float floatx2;
typedef __attribute__((ext_vector_type(4))) unsigned int uintx4;
typedef __attribute__((ext_vector_type(2))) unsigned int uintx2;
typedef __attribute__((ext_vector_type(2))) __bf16 bf16x2;

#define LOG2E 1.44269504f

__device__ __forceinline__ float bf2f(u16 u){
  union { unsigned int i; float f; } v; v.i = ((unsigned int)u) << 16; return v.f;
}
__device__ __forceinline__ u16 f2bf(float f){
  union { __bf16 b; u16 u; } v; v.b = (__bf16)f; return v.u;
}
// packed f32x2 -> bf16x2 (v_cvt_pk_bf16_f32, RNE)
__device__ __forceinline__ unsigned int pk2(float a, float b){
  union { bf16x2 h; unsigned int u; } v;
  v.h = __builtin_convertvector((floatx2){a, b}, bf16x2);
  return v.u;
}
// async global->LDS, 16B per lane (dest = wave-uniform base + lane*16)
__device__ __forceinline__ void gload16(const void* g, void* l){
  __builtin_amdgcn_global_load_lds((const __attribute__((address_space(1))) unsigned int*)g,
                                   (__attribute__((address_space(3))) unsigned int*)l, 16, 0, 0);
}
// load 8 fp32 from g, convert to 8 bf16 packed in a uintx4
__device__ __forceinline__ uintx4 ld8f_bf(const float* g){
  floatx4 u0 = *(const floatx4*)g;
  floatx4 u1 = *(const floatx4*)(g + 4);
  uintx4 w;
  w.x = pk2(u0.x, u0.y); w.y = pk2(u0.z, u0.w);
  w.z = pk2(u1.x, u1.y); w.w = pk2(u1.z, u1.w);
  return w;
}
__device__ __forceinline__ float redq(float v){   // sum across quads (lanes ^16, ^32)
  v += __shfl_xor(v, 16); v += __shfl_xor(v, 32);
  return v;
}

// ---------------- prep kernels ----------------
__global__ void transpose_w(const float* __restrict__ qkv_w, const float* __restrict__ anchor_w,
                            const float* __restrict__ proj_w,
                            u16* __restrict__ qkvt, u16* __restrict__ anct, u16* __restrict__ projt){
  int id = blockIdx.x*256 + threadIdx.x;
  if (id < 196608){ int k = id / 768, n = id % 768; qkvt[n*256 + k] = f2bf(qkv_w[id]); }
  else if (id < 229376){ int r = id - 196608; int k = r / 128, n = r % 128; anct[n*256 + k] = f2bf(anchor_w[r]); }
  else { int r = id - 229376; int k = r >> 8, n = r & 255; projt[n*256 + k] = f2bf(proj_w[r]); }
}

__global__ void cpb_mlp(const float* __restrict__ tw, const float* __restrict__ ts,
                        const float* __restrict__ w1w, const float* __restrict__ b1w, const float* __restrict__ w2w,
                        const float* __restrict__ w1s1, const float* __restrict__ b1s1, const float* __restrict__ w2s1,
                        const float* __restrict__ w1s2, const float* __restrict__ b1s2, const float* __restrict__ w2s2,
                        float* __restrict__ btw, float* __restrict__ bts1, float* __restrict__ bts2){
  int tag = blockIdx.y;
  const float *tab, *w1, *b1, *w2; float* bt; int T;
  if (tag == 0){ tab = tw; w1 = w1w;  b1 = b1w;  w2 = w2w;  bt = btw;  T = 961; }
  else if (tag == 1){ tab = ts; w1 = w1s1; b1 = b1s1; w2 = w2s1; bt = bts1; T = 1521; }
  else { tab = ts; w1 = w1s2; b1 = b1s2; w2 = w2s2; bt = bts2; T = 1521; }
  __shared__ float sw1[2][512];
  __shared__ float sb1[512];
  __shared__ float sw2[512][4];
  for (int j = threadIdx.x; j < 512; j += 256){
    sw1[0][j] = w1[j]; sw1[1][j] = w1[512 + j]; sb1[j] = b1[j];
    for (int h = 0; h < 4; ++h) sw2[j][h] = w2[j*4 + h];
  }
  __syncthreads();
  int idx = blockIdx.x*256 + threadIdx.x;
  int r = idx >> 2, hh = idx & 3;
  if (r < T){
    float t0 = tab[2*r], t1 = tab[2*r + 1];
    float acc = 0.f;
    for (int j = 0; j < 512; ++j){
      float hj = fmaxf(fmaf(t0, sw1[0][j], fmaf(t1, sw1[1][j], sb1[j])), 0.f);
      acc = fmaf(hj, sw2[j][hh], acc);
    }
    bt[r*4 + hh] = acc;
  }
}

// bias tables pre-folded: (16*sigmoid(v) - off_h) * log2(e), off_h = min(scale_h+16, 80)
// laid out so attention loads are query-contiguous floatx4 per key-quad.
__global__ void bias_gather(const float* __restrict__ btw, const float* __restrict__ bts1,
                            const float* __restrict__ bts2,
                            const int* __restrict__ idxw, const int* __restrict__ idxa2w,
                            const int* __restrict__ idxw2a,
                            const float* __restrict__ lsw, const float* __restrict__ ls1,
                            const float* __restrict__ ls2,
                            float* __restrict__ bw, float* __restrict__ bs1, float* __restrict__ bs2){
  int id = blockIdx.x*256 + threadIdx.x;     // 3 * 262144
  int which = id >> 18;
  int rem = id & 262143;
  int h = rem >> 16, e = rem & 65535;
  const float* bt; const int* ix; float* dst; const float* ls;
  if (which == 0){ bt = btw;  ix = idxw;   dst = bw;  ls = lsw; }
  else if (which == 1){ bt = bts1; ix = idxa2w; dst = bs1; ls = ls1; }
  else { bt = bts2; ix = idxw2a; dst = bs2; ls = ls2; }
  float v = bt[ix[e]*4 + h];
  float scale = exp2f(fminf(ls[h], 4.6051702f) * LOG2E);
  float off = fminf(scale + 16.f, 80.f);
  float sig = 16.f / (1.f + exp2f(-v * LOG2E));
  float out = (sig - off) * LOG2E;
  int idx;
  if (which == 0){
    int q = e >> 8, k = e & 255;
    idx = ((((h*8 + (k>>5))*2 + ((k>>4)&1))*4 + ((k>>2)&3)) << 10) + (q << 2) + (k & 3);
  } else if (which == 1){
    int a = e >> 10, k = e & 1023;
    idx = (((h*64 + (k>>4))*4 + ((k>>2)&3)) << 8) + (a << 2) + (k & 3);
  } else {
    int q = e >> 6, k = e & 63;
    idx = (((h*4 + (k>>4))*4 + ((k>>2)&3)) << 12) + (q << 2) + (k & 3);
  }
  dst[idx] = out;
}

__global__ void avgpool(const float* __restrict__ x, float* __restrict__ pooled){
  int a = blockIdx.x, c = threadIdx.x;
  int ay = a >> 6, ax = a & 63;
  float acc = 0.f;
#pragma unroll
  for (int dy = 0; dy < 4; ++dy)
#pragma unroll
    for (int dx = 0; dx < 4; ++dx)
      acc += x[(size_t)((ay*4 + dy)*256 + ax*4 + dx)*256 + c];
  pooled[(size_t)a*256 + c] = acc * 0.0625f;
}

// ---------------- fused GEMM: C[M, NY*128](bf16) = A[M,256](f32) @ Bt^T + bias ----------------
// A-tile persists in LDS (staged once, 64 KB); B streamed per y-slice in 8 KB dbuf chunks.
// y < normY -> per-(row, 32-col head) L2 normalize. Swapped MFMA: acc r runs along cols.
__launch_bounds__(256, 2)
__global__ void gemm_fused(const float* __restrict__ A, const u16* __restrict__ Bt,
                           const float* __restrict__ bias, u16* __restrict__ C,
                           int NY, int normY){
  __shared__ __align__(16) u16 lsA[32768];     // 64 KB: [k8 0..31][128 rows (skew k8*2)][8]
  __shared__ __align__(16) u16 lsB[2][4096];   // 2 x 8 KB: [128 rows][32 k] linear
  const int tid = threadIdx.x, lane = tid & 63, wv = tid >> 6;
  const int lane15 = lane & 15, quad = lane >> 4;
  const int wr = wv >> 1, wc = wv & 1;
  const int m0 = blockIdx.x * 128;
  const int N = NY * 128;
  const int brow = wv*16 + (lane >> 2);
  const int bk = (lane & 3)*8;
  auto stageB = [&](int y, int kw, int buf){
    const u16* bs = Bt + (size_t)(y*128 + brow)*256 + kw*32 + bk;
    char* d = (char*)lsB[buf];
    gload16(bs,            d + wv*1024);
    gload16(bs + 64*256,   d + 4096 + wv*1024);
  };
  stageB(0, 0, 0);       // in flight during A staging
  { // ---- stage A once: 128 rows x 256 k, f32 -> bf16 ----
    const int row = tid & 127, kh = tid >> 7;
    const float* ap = A + (size_t)(m0 + row)*256 + kh*128;
#pragma unroll
    for (int i = 0; i < 16; ++i){
      int k8 = kh*16 + i;
      uintx4 w = ld8f_bf(ap + i*8);
      *(uintx4*)(lsA + ((size_t)k8*128 + ((row + k8*2) & 127))*8) = w;
    }
  }
  for (int y = 0; y < NY; ++y){
    floatx4 acc[4][4] = {};
    for (int kw = 0; kw < 8; ++kw){
      const int it = y*8 + kw;
      __syncthreads();                       // drains B(it) DMA (+ A stage on it==0)
      if (it + 1 < NY*8){
        int nit = it + 1;
        stageB(nit >> 3, nit & 7, nit & 1);
      }
      const char* Bc = (const char*)lsB[it & 1];
      const int k8 = kw*4 + quad;
      short8 a[4], b[4];
#pragma unroll
      for (int i = 0; i < 4; ++i)
        a[i] = *(const short8*)(lsA + ((size_t)k8*128 + ((wr*64 + i*16 + lane15 + k8*2) & 127))*8);
#pragma unroll
      for (int j = 0; j < 4; ++j)
        b[j] = *(const short8*)(Bc + (wc*64 + j*16 + lane15)*64 + quad*16);
#pragma unroll
      for (int i = 0; i < 4; ++i)
#pragma unroll
        for (int j = 0; j < 4; ++j)
          acc[i][j] = __builtin_amdgcn_mfma_f32_16x16x32_bf16(b[j], a[i], acc[i][j], 0, 0, 0);
    }
    // ---- epilogue for slice y ----
#pragma unroll
    for (int j = 0; j < 4; ++j){
      floatx4 bz = *(const floatx4*)(bias + y*128 + wc*64 + j*16 + quad*4);
#pragma unroll
      for (int i = 0; i < 4; ++i) acc[i][j] += bz;
    }
    if (y < normY){
#pragma unroll
      for (int i = 0; i < 4; ++i)
#pragma unroll
        for (int jp = 0; jp < 2; ++jp){
          floatx4 s2 = acc[i][jp*2]*acc[i][jp*2] + acc[i][jp*2+1]*acc[i][jp*2+1];
          float ss = (s2.x + s2.y) + (s2.z + s2.w);
          ss = redq(ss);
          float inv = 1.f / fmaxf(sqrtf(ss), 1e-12f);
          acc[i][jp*2]   *= inv;
          acc[i][jp*2+1] *= inv;
        }
    }
#pragma unroll
    for (int i = 0; i < 4; ++i){
      int row = m0 + wr*64 + i*16 + lane15;
#pragma unroll
      for (int j = 0; j < 4; ++j){
        int colb = y*128 + wc*64 + j*16 + quad*4;
        uintx2 w;
        w.x = pk2(acc[i][j][0], acc[i][j][1]);
        w.y = pk2(acc[i][j][2], acc[i][j][3]);
        *(uintx2*)(C + (size_t)row*N + colb) = w;
      }
    }
  }
}

// ---------------- proj GEMM: Cout[M,256](f32) = Ab[M,256](bf16) @ Bt^T + bias ----------------
// both operands DMA-staged (m97 pattern), 32 MFMA per barrier.
__launch_bounds__(256, 2)
__global__ void gemm_proj(const u16* __restrict__ Ab, const u16* __restrict__ Bt,
                          const float* __restrict__ bias, float* __restrict__ Cout){
  __shared__ __align__(16) u16 lsA[2][4096];   // [buf][128 rows][32 k]
  __shared__ __align__(16) u16 lsB[2][8192];   // [buf][256 rows][32 k]
  const int tid = threadIdx.x, lane = tid & 63, wv = tid >> 6;
  const int lane15 = lane & 15, quad = lane >> 4;
  const int wr = wv >> 1, wc = wv & 1;     // wave = 64 rows x 128 cols
  const int m0 = blockIdx.x * 128;
  const int srow = wv*16 + (lane >> 2), sk = (lane & 3)*8;
  const u16* as = Ab + (size_t)(m0 + srow)*256 + sk;
  const u16* bs = Bt + (size_t)srow*256 + sk;
  auto stage = [&](int kw, int buf){
    char* dA = (char*)lsA[buf]; char* dB = (char*)lsB[buf];
    gload16(as + kw*32,             dA + wv*1024);
    gload16(as + 64*256 + kw*32,    dA + 4096  + wv*1024);
    gload16(bs + kw*32,             dB + wv*1024);
    gload16(bs + 64*256 + kw*32,    dB + 4096  + wv*1024);
    gload16(bs + 128*256 + kw*32,   dB + 8192  + wv*1024);
    gload16(bs + 192*256 + kw*32,   dB + 12288 + wv*1024);
  };
  stage(0, 0);
  floatx4 acc[4][8] = {};
  for (int kw = 0; kw < 8; ++kw){
    __syncthreads();
    if (kw < 7) stage(kw + 1, (kw + 1) & 1);
    const char* Ac = (const char*)lsA[kw & 1];
    const char* Bc = (const char*)lsB[kw & 1];
    short8 a[4], b[8];
#pragma unroll
    for (int i = 0; i < 4; ++i)
      a[i] = *(const short8*)(Ac + (wr*64 + i*16 + lane15)*64 + quad*16);
#pragma unroll
    for (int j = 0; j < 8; ++j)
      b[j] = *(const short8*)(Bc + (wc*128 + j*16 + lane15)*64 + quad*16);
#pragma unroll
    for (int i = 0; i < 4; ++i)
#pragma unroll
      for (int j = 0; j < 8; ++j)
        acc[i][j] = __builtin_amdgcn_mfma_f32_16x16x32_bf16(b[j], a[i], acc[i][j], 0, 0, 0);
  }
#pragma unroll
  for (int i = 0; i < 4; ++i){
    int row = m0 + wr*64 + i*16 + lane15;
#pragma unroll
    for (int j = 0; j < 8; ++j){
      int colb = wc*128 + j*16 + quad*4;
      floatx4 bz = *(const floatx4*)(bias + colb);
      floatx4 o = acc[i][j] + bz;
      *(floatx4*)(Cout + (size_t)row*256 + colb) = o;
    }
  }
}

// ---------------- window attention (S^T formulation), full image ----------------
// qkvh: [65536][384] bf16, Qn[0,128) Kn[128,256) V[256,384); grid (256 windows, 4 heads)
__launch_bounds__(256, 3)
__global__ void win_attn(const u16* __restrict__ qkvh, const float* __restrict__ lsw,
                         const float* __restrict__ biasw, u16* __restrict__ outm){
  __shared__ __align__(16) u16 sm[24576];   // 48 KB: K[0,8192) Q[8192,16384)->P  VT[16384,24576)
  const int tid = threadIdx.x, lane = tid & 63, wv = tid >> 6;
  const int lane15 = lane & 15, quad = lane >> 4;
  const int h = blockIdx.y;
  const int wyl = blockIdx.x >> 4, wx = blockIdx.x & 15;
  u16* Ks = sm;
  u16* Qs = sm + 8192;
  u16* VT = sm + 16384;
  { // stage: DMA Q,K (pre-normalized) into k-outer [kq][256 tok][8]; V scalar-transposed
    int tok = wv*64 + lane;
    int row = (wyl*16 + (tok >> 4))*256 + wx*16 + (tok & 15);
    const char* src = (const char*)qkvh + (size_t)row*768 + h*64;
#pragma unroll
    for (int kq = 0; kq < 4; ++kq){
      gload16(src + kq*16,        (char*)Qs + wv*1024 + kq*4096);
      gload16(src + 256 + kq*16,  (char*)Ks + wv*1024 + kq*4096);
    }
    int vrow = (wyl*16 + (tid >> 4))*256 + wx*16 + (tid & 15);
    const uintx4* vp = (const uintx4*)((const char*)qkvh + (size_t)vrow*768 + 512 + h*64);
    uintx4 v0 = vp[0], v1 = vp[1], v2 = vp[2], v3 = vp[3];
    unsigned int w[16] = {v0.x,v0.y,v0.z,v0.w, v1.x,v1.y,v1.z,v1.w,
                          v2.x,v2.y,v2.z,v2.w, v3.x,v3.y,v3.z,v3.w};
    u16* vd = VT + (tid >> 3)*256 + (tid & 7);
#pragma unroll
    for (int c = 0; c < 16; ++c){
      vd[(c*2)*8]   = (u16)(w[c] & 0xffffu);
      vd[(c*2+1)*8] = (u16)(w[c] >> 16);
    }
  }
  __syncthreads();
  short8 qf[4];                 // wave owns queries wv*64 .. +63 (B-operand)
#pragma unroll
  for (int j = 0; j < 4; ++j)
    qf[j] = *(const short8*)(Qs + quad*2048 + (wv*64 + j*16 + lane15)*8);
  __syncthreads();              // all Q reads done before P overwrites

  float scale = exp2f(fminf(lsw[h], 4.6051702f) * LOG2E) * LOG2E;
  u16* Pw = Qs + wv*2048;       // per-wave P^T: [4 key-octs][64 queries][8]
  const floatx4 zf4 = {0.f, 0.f, 0.f, 0.f};
  floatx4 accO[2][4] = {};      // O^T: [d-tile][query-tile]
  float lsum[4] = {};

  for (int kc = 0; kc < 8; ++kc){      // 32 keys per chunk
    floatx4 bia[2][4];
#pragma unroll
    for (int i = 0; i < 2; ++i)
#pragma unroll
      for (int j = 0; j < 4; ++j)
        bia[i][j] = *(const floatx4*)(biasw + ((((h*8 + kc)*2 + i)*4 + quad) << 10)
                                            + ((wv*64 + j*16 + lane15) << 2));
    short8 kf[2];
#pragma unroll
    for (int i = 0; i < 2; ++i)
      kf[i] = *(const short8*)(Ks + quad*2048 + (kc*32 + i*16 + lane15)*8);
#pragma unroll
    for (int i = 0; i < 2; ++i)
#pragma unroll
      for (int j = 0; j < 4; ++j){
        floatx4 sv = __builtin_amdgcn_mfma_f32_16x16x32_bf16(kf[i], qf[j], zf4, 0, 0, 0);
        float p0 = exp2f(fmaf(sv[0], scale, bia[i][j][0]));
        float p1 = exp2f(fmaf(sv[1], scale, bia[i][j][1]));
        float p2 = exp2f(fmaf(sv[2], scale, bia[i][j][2]));
        float p3 = exp2f(fmaf(sv[3], scale, bia[i][j][3]));
        lsum[j] += (p0 + p1) + (p2 + p3);
        uintx2 w; w.x = pk2(p0, p1); w.y = pk2(p2, p3);
        *(uintx2*)(Pw + (i*2 + (quad>>1))*512 + (j*16 + lane15)*8 + (quad&1)*4) = w;
      }
    asm volatile("s_waitcnt lgkmcnt(0)" ::: "memory");
    short8 ptf[4], vtf[2];
#pragma unroll
    for (int j = 0; j < 4; ++j)
      ptf[j] = *(const short8*)(Pw + quad*512 + (j*16 + lane15)*8);
#pragma unroll
    for (int m = 0; m < 2; ++m)
      vtf[m] = *(const short8*)(VT + (kc*4 + quad)*256 + (m*16 + lane15)*8);
#pragma unroll
    for (int m = 0; m < 2; ++m)
#pragma unroll
      for (int j = 0; j < 4; ++j)
        accO[m][j] = __builtin_amdgcn_mfma_f32_16x16x32_bf16(vtf[m], ptf[j], accO[m][j], 0, 0, 0);
  }
  float linv[4];
#pragma unroll
  for (int j = 0; j < 4; ++j) linv[j] = 1.f / redq(lsum[j]);
#pragma unroll
  for (int m = 0; m < 2; ++m)
#pragma unroll
    for (int j = 0; j < 4; ++j){
      int tok = wv*64 + j*16 + lane15;
      int py = wyl*16 + (tok >> 4), px = wx*16 + (tok & 15);
      floatx4 o = accO[m][j] * linv[j];
      uintx2 w; w.x = pk2(o[0], o[1]); w.y = pk2(o[2], o[3]);
      *(uintx2*)(outm + (size_t)(py*256 + px)*256 + h*32 + m*16 + quad*4) = w;
    }
}

// ---------------- stripe phase 1: xm partials (key-split), full image ----------------
// grid (64 stripes, 4 heads, 2 key-halves)
__launch_bounds__(256, 3)
__global__ void stripe_xm(const u16* __restrict__ qkvh, const u16* __restrict__ anchor,
                          const float* __restrict__ ls1, const float* __restrict__ bias1,
                          float* __restrict__ gl1, u16* __restrict__ gO){
  __shared__ __align__(16) u16 sm[22528];  // ANC[0,2048) KC0[2048,6144) KC1[6144,10240) VT[10240,14336) P1T[14336,22528)
  const int tid = threadIdx.x, lane = tid & 63, wv = tid >> 6;
  const int lane15 = lane & 15, quad = lane >> 4;
  const int s = blockIdx.x, h = blockIdx.y, kb = blockIdx.z;
  const int syl = s >> 3, sx = s & 7;
  u16* ANC = sm; u16* VT = sm + 10240; u16* P1T = sm + 14336;
  if (wv == 0){   // anchors pre-normalized in anch
    int ay = syl*8 + (lane >> 3), ax = sx*8 + (lane & 7);
    const char* asrc = (const char*)anchor + (size_t)(ay*64 + ax)*256 + h*64;
#pragma unroll
    for (int kq = 0; kq < 4; ++kq)
      gload16(asrc + kq*16, (char*)ANC + kq*1024);
  }
  auto stageK = [&](int kc){
    int kkb = kb*512 + kc*128;
    char* KC = (char*)sm + 4096 + (kc & 1)*8192;
#pragma unroll
    for (int hf = 0; hf < 2; ++hf){
      int tok = kkb + hf*64 + lane;
      int row = (syl*32 + (tok >> 5))*256 + sx*32 + (tok & 31);
      gload16((const char*)qkvh + (size_t)row*768 + 256 + h*64 + wv*16,
              KC + wv*2048 + hf*1024);
    }
  };
  stageK(0);
  float scale1 = exp2f(fminf(ls1[h], 4.6051702f) * LOG2E) * LOG2E;
  const floatx4 zf4 = {0.f, 0.f, 0.f, 0.f};
  floatx4 accO1[2] = {};
  float l1 = 0.f;
  for (int kc = 0; kc < 4; ++kc){
    int kkb = kb*512 + kc*128;
    { // stage V(kc): token tid>>1, d-half tid&1; direct u16 transpose
      int tok_l = tid >> 1, dh = tid & 1;
      int tok = kkb + tok_l;
      int row = (syl*32 + (tok >> 5))*256 + sx*32 + (tok & 31);
      const uintx4* vp = (const uintx4*)((const char*)qkvh + (size_t)row*768 + 512 + h*64 + dh*32);
      uintx4 v0 = vp[0], v1 = vp[1];
      unsigned int w[8] = {v0.x,v0.y,v0.z,v0.w, v1.x,v1.y,v1.z,v1.w};
      u16* vd = VT + (tok_l >> 3)*256 + dh*128 + (tok_l & 7);
#pragma unroll
      for (int c = 0; c < 8; ++c){
        vd[(c*2)*8]   = (u16)(w[c] & 0xffffu);
        vd[(c*2+1)*8] = (u16)(w[c] >> 16);
      }
    }
    __syncthreads();                       // VT visible; KC(kc) DMA drained; ANC ready
    if (kc < 3) stageK(kc + 1);            // overlaps compute, drains at end barrier
    const u16* KC = sm + 2048 + (kc & 1)*4096;
    short8 ancf = *(const short8*)(ANC + quad*512 + (wv*16 + lane15)*8);
    floatx4 bia[8];
#pragma unroll
    for (int i = 0; i < 8; ++i)
      bia[i] = *(const floatx4*)(bias1 + (((h*64 + kb*32 + kc*8 + i)*4 + quad) << 8)
                                       + ((wv*16 + lane15) << 2));
#pragma unroll
    for (int i = 0; i < 8; ++i){
      short8 kf = *(const short8*)(KC + quad*1024 + (i*16 + lane15)*8);
      floatx4 sv = __builtin_amdgcn_mfma_f32_16x16x32_bf16(kf, ancf, zf4, 0, 0, 0);
      float p0 = exp2f(fmaf(sv[0], scale1, bia[i][0]));
      float p1 = exp2f(fmaf(sv[1], scale1, bia[i][1]));
      float p2 = exp2f(fmaf(sv[2], scale1, bia[i][2]));
      float p3 = exp2f(fmaf(sv[3], scale1, bia[i][3]));
      l1 += (p0 + p1) + (p2 + p3);
      uintx2 w; w.x = pk2(p0, p1); w.y = pk2(p2, p3);
      *(uintx2*)(P1T + (i*2 + (quad>>1))*512 + (wv*16 + lane15)*8 + (quad&1)*4) = w;
    }
    asm volatile("s_waitcnt lgkmcnt(0)" ::: "memory");
#pragma unroll
    for (int ks = 0; ks < 4; ++ks){
      short8 ptf = *(const short8*)(P1T + (ks*4 + quad)*512 + (wv*16 + lane15)*8);
#pragma unroll
      for (int m = 0; m < 2; ++m){
        short8 vtf = *(const short8*)(VT + (ks*4 + quad)*256 + (m*16 + lane15)*8);
        accO1[m] = __builtin_amdgcn_mfma_f32_16x16x32_bf16(vtf, ptf, accO1[m], 0, 0, 0);
      }
    }
    __syncthreads();   // protect VT/P1T before next-iter staging
  }
  l1 = redq(l1);
  int ent = (s*4 + h)*2 + kb;
  if (quad == 0) gl1[ent*64 + wv*16 + lane15] = l1;
#pragma unroll
  for (int m = 0; m < 2; ++m){
    uintx2 w; w.x = pk2(accO1[m][0], accO1[m][1]); w.y = pk2(accO1[m][2], accO1[m][3]);
    *(uintx2*)(gO + (size_t)ent*2048 + (wv*16 + lane15)*32 + m*16 + quad*4) = w;
  }
}

// ---------------- stripe phase 2: xs, full image ----------------
// grid (64 stripes * 4 query-chunks, 4 heads)
__launch_bounds__(256, 3)
__global__ void stripe_xs(const u16* __restrict__ qkvh, const u16* __restrict__ anchor,
                          const float* __restrict__ ls2, const float* __restrict__ bias2,
                          const float* __restrict__ gl1, const u16* __restrict__ gO,
                          u16* __restrict__ outm){
  __shared__ __align__(16) u16 sm[20480]; // ANC[0,2048) XMT[2048,4096) QW[4096+wv*2048) P2T[12288+wv*2048)
  const int tid = threadIdx.x, lane = tid & 63, wv = tid >> 6;
  const int lane15 = lane & 15, quad = lane >> 4;
  const int s = blockIdx.x >> 2, qc = blockIdx.x & 3, h = blockIdx.y;
  const int syl = s >> 3, sx = s & 7;
  u16* ANC = sm;
  u16* XMT = sm + 2048;
  u16* QW  = sm + 4096 + wv*2048;
  u16* P2T = sm + 12288 + wv*2048;
  if (wv == 0){
    int ay = syl*8 + (lane >> 3), ax = sx*8 + (lane & 7);
    const char* asrc = (const char*)anchor + (size_t)(ay*64 + ax)*256 + h*64;
#pragma unroll
    for (int kq = 0; kq < 4; ++kq)
      gload16(asrc + kq*16, (char*)ANC + kq*1024);
  }
  { // combine xm partials -> XMT [anchor-oct][d 32][8] bf16
    int a = tid >> 2, db = (tid & 3)*8;
    int e0 = (s*4 + h)*2;
    float inv = 1.f / (gl1[e0*64 + a] + gl1[(e0 + 1)*64 + a]);
    uintx4 u0 = *(const uintx4*)(gO + (size_t)e0*2048 + a*32 + db);
    uintx4 u1 = *(const uintx4*)(gO + (size_t)(e0 + 1)*2048 + a*32 + db);
    unsigned int w0[4] = {u0.x, u0.y, u0.z, u0.w};
    unsigned int w1[4] = {u1.x, u1.y, u1.z, u1.w};
#pragma unroll
    for (int c = 0; c < 4; ++c){
      float a0 = bf2f((u16)(w0[c] & 0xffffu)) + bf2f((u16)(w1[c] & 0xffffu));
      float a1 = bf2f((u16)(w0[c] >> 16))     + bf2f((u16)(w1[c] >> 16));
      XMT[(a >> 3)*256 + (db + c*2)*8     + (a & 7)] = f2bf(a0 * inv);
      XMT[(a >> 3)*256 + (db + c*2 + 1)*8 + (a & 7)] = f2bf(a1 * inv);
    }
  }
  int tq = qc*256 + wv*64;     // query base within stripe (wave owns 64)
  { // DMA stage this wave's 64 queries (pre-normalized)
    int tok = tq + lane;
    int row = (syl*32 + (tok >> 5))*256 + sx*32 + (tok & 31);
    const char* src = (const char*)qkvh + (size_t)row*768 + h*64;
#pragma unroll
    for (int kq = 0; kq < 4; ++kq)
      gload16(src + kq*16, (char*)QW + kq*1024);
  }
  __syncthreads();
  short8 qf2[4];
#pragma unroll
  for (int j = 0; j < 4; ++j)
    qf2[j] = *(const short8*)(QW + quad*512 + (j*16 + lane15)*8);
  float scale2 = exp2f(fminf(ls2[h], 4.6051702f) * LOG2E) * LOG2E;
  const floatx4 zf4 = {0.f, 0.f, 0.f, 0.f};
  floatx4 accO2[2][4] = {};
  float l2[4] = {};
#pragma unroll
  for (int c = 0; c < 2; ++c){      // 2 anchor chunks of 32
    floatx4 bia[2][4];
#pragma unroll
    for (int i = 0; i < 2; ++i)
#pragma unroll
      for (int j = 0; j < 4; ++j)
        bia[i][j] = *(const floatx4*)(bias2 + ((((h*4 + c*2 + i)*4 + quad) << 12)
                                             + ((tq + j*16 + lane15) << 2)));
    short8 af[2];
#pragma unroll
    for (int i = 0; i < 2; ++i)
      af[i] = *(const short8*)(ANC + quad*512 + (c*32 + i*16 + lane15)*8);
#pragma unroll
    for (int i = 0; i < 2; ++i)
#pragma unroll
      for (int j = 0; j < 4; ++j){
        floatx4 sv = __builtin_amdgcn_mfma_f32_16x16x32_bf16(af[i], qf2[j], zf4, 0, 0, 0);
        float p0 = exp2f(fmaf(sv[0], scale2, bia[i][j][0]));
        float p1 = exp2f(fmaf(sv[1], scale2, bia[i][j][1]));
        float p2 = exp2f(fmaf(sv[2], scale2, bia[i][j][2]));
        float p3 = exp2f(fmaf(sv[3], scale2, bia[i][j][3]));
        l2[j] += (p0 + p1) + (p2 + p3);
        uintx2 w; w.x = pk2(p0, p1); w.y = pk2(p2, p3);
        *(uintx2*)(P2T + (i*2 + (quad>>1))*512 + (j*16 + lane15)*8 + (quad&1)*4) = w;
      }
    asm volatile("s_waitcnt lgkmcnt(0)" ::: "memory");
    short8 ptf[4], xmf[2];
#pragma unroll
    for (int j = 0; j < 4; ++j)
      ptf[j] = *(const short8*)(P2T + quad*512 + (j*16 + lane15)*8);
#pragma unroll
    for (int m = 0; m < 2; ++m)
      xmf[m] = *(const short8*)(XMT + (c*4 + quad)*256 + (m*16 + lane15)*8);
#pragma unroll
    for (int m = 0; m < 2; ++m)
#pragma unroll
      for (int j = 0; j < 4; ++j)
        accO2[m][j] = __builtin_amdgcn_mfma_f32_16x16x32_bf16(xmf[m], ptf[j], accO2[m][j], 0, 0, 0);
  }
  float linv[4];
#pragma unroll
  for (int j = 0; j < 4; ++j) linv[j] = 1.f / redq(l2[j]);
#pragma unroll
  for (int m = 0; m < 2; ++m)
#pragma unroll
    for (int j = 0; j < 4; ++j){
      int tok = tq + j*16 + lane15;
      int py = syl*32 + (tok >> 5), px = sx*32 + (tok & 31);
      floatx4 o = accO2[m][j] * linv[j];
      uintx2 w; w.x = pk2(o[0], o[1]); w.y = pk2(o[2], o[3]);
      *(uintx2*)(outm + (size_t)(py*256 + px)*256 + 128 + h*32 + m*16 + quad*4) = w;
    }
}

// ---------------- launch ----------------
extern "C" void kernel_launch(void* const* d_in, const int* in_sizes, int n_in,
                              void* d_out, int out_size, void* d_ws, size_t ws_size,
                              hipStream_t stream) {
  (void)in_sizes; (void)n_in; (void)out_size; (void)ws_size;
  const float* x        = (const float*)d_in[0];
  const float* qkv_w    = (const float*)d_in[1];
  const float* qkv_b    = (const float*)d_in[2];
  const float* anchor_w = (const float*)d_in[3];
  const float* anchor_b = (const float*)d_in[4];
  const float* ls_w     = (const float*)d_in[5];
  const float* w1_w     = (const float*)d_in[6];
  const float* b1_w     = (const float*)d_in[7];
  const float* w2_w     = (const float*)d_in[8];
  const float* ls_s1    = (const float*)d_in[9];
  const float* w1_s1    = (const float*)d_in[10];
  const float* b1_s1    = (const float*)d_in[11];
  const float* w2_s1    = (const float*)d_in[12];
  const float* ls_s2    = (const float*)d_in[13];
  const float* w1_s2    = (const float*)d_in[14];
  const float* b1_s2    = (const float*)d_in[15];
  const float* w2_s2    = (const float*)d_in[16];
  const float* proj_w   = (const float*)d_in[17];
  const float* proj_b   = (const float*)d_in[18];
  const float* table_w  = (const float*)d_in[19];
  const float* table_s  = (const float*)d_in[20];
  const int* index_w   = (const int*)d_in[21];
  const int* index_a2w = (const int*)d_in[22];
  const int* index_w2a = (const int*)d_in[23];

  // ---- workspace layout (~138.8 MB; ws is 256 MiB per poison-fill WRITE_SIZE) ----
  char* ws = (char*)d_ws;
  u16*   qkvhW  = (u16*)(ws + 0);                  // 65536*384 bf16 = 50331648 B
  u16*   qkvhS  = (u16*)(ws + 50331648);           // 65536*384 bf16
  u16*   mergedb= (u16*)(ws + 100663296);          // 65536*256 bf16 = 33554432 B
  float* pooled = (float*)(ws + 134217728);        // 4096*256 f32 = 4 MB
  u16*   anch   = (u16*)(ws + 138412032);          // 4096*128 bf16 = 1 MB
  u16*   qkvt   = (u16*)(ws + 139460608);          // 768*256 bf16
  u16*   anct   = (u16*)(ws + 139853824);          // 128*256 bf16
  u16*   projt  = (u16*)(ws + 139919360);          // 256*256 bf16
  float* btw    = (float*)(ws + 140050432);
  float* bts1   = (float*)(ws + 140066816);
  float* bts2   = (float*)(ws + 140091392);
  float* biasw  = (float*)(ws + 140115968);        // 4*65536 f32 = 1 MB
  float* bias1  = (float*)(ws + 141164544);        // 1 MB
  float* bias2  = (float*)(ws + 142213120);        // 1 MB
  float* gl1    = (float*)(ws + 143261696);        // 512*64 f32 = 128 KB
  u16*   gO     = (u16*)(ws + 143392768);          // 512*2048 bf16 = 2 MB (end 145489920)

  transpose_w<<<1152, 256, 0, stream>>>(qkv_w, anchor_w, proj_w, qkvt, anct, projt);
  cpb_mlp<<<dim3(24, 3), 256, 0, stream>>>(table_w, table_s,
                                           w1_w, b1_w, w2_w,
                                           w1_s1, b1_s1, w2_s1,
                                           w1_s2, b1_s2, w2_s2,
                                           btw, bts1, bts2);
  bias_gather<<<3072, 256, 0, stream>>>(btw, bts1, bts2, index_w, index_a2w, index_w2a,
                                        ls_w, ls_s1, ls_s2, biasw, bias1, bias2);
  avgpool<<<4096, 256, 0, stream>>>(x, pooled);
  // anchor projection (NY=1, normalized)
  gemm_fused<<<32, 256, 0, stream>>>(pooled, anct, anchor_b, anch, 1, 1);
  // window branch qkv (full image): Qn|Kn|V
  gemm_fused<<<512, 256, 0, stream>>>(x, qkvt, qkv_b, qkvhW, 3, 2);
  win_attn<<<dim3(256, 4), 256, 0, stream>>>(qkvhW, ls_w, biasw, mergedb);
  // stripe branch qkv (full image)
  gemm_fused<<<512, 256, 0, stream>>>(x, qkvt + 384*256, qkv_b + 384, qkvhS, 3, 2);
  stripe_xm<<<dim3(64, 4, 2), 256, 0, stream>>>(qkvhS, anch, ls_s1, bias1, gl1, gO);
  stripe_xs<<<dim3(256, 4), 256, 0, stream>>>(qkvhS, anch, ls_s2, bias2, gl1, gO, mergedb);
  // output projection: bf16 merged -> f32 d_out
  gemm_proj<<<512, 256, 0, stream>>>(mergedb, projt, proj_b, (float*)d_out);
}

// Round 6
// 351.037 us; speedup vs baseline: 1.2061x; 1.0004x over previous
//
#include <hip/hip_runtime.h>
#include <cstdint>
#include <cstddef>

typedef unsigned short u16;
typedef __attribute__((ext_vector_type(8))) short short8;
typedef __attribute__((ext_vector_type(4))) float floatx4;
typedef __attribute__((ext_vector_type(2))) float floatx2;
typedef __attribute__((ext_vector_type(4))) unsigned int uintx4;
typedef __attribute__((ext_vector_type(2))) unsigned int uintx2;
typedef __attribute__((ext_vector_type(2))) __bf16 bf16x2;

#define LOG2E 1.44269504f

__device__ __forceinline__ float bf2f(u16 u){
  union { unsigned int i; float f; } v; v.i = ((unsigned int)u) << 16; return v.f;
}
__device__ __forceinline__ u16 f2bf(float f){
  union { __bf16 b; u16 u; } v; v.b = (__bf16)f; return v.u;
}
// packed f32x2 -> bf16x2 (v_cvt_pk_bf16_f32, RNE)
__device__ __forceinline__ unsigned int pk2(float a, float b){
  union { bf16x2 h; unsigned int u; } v;
  v.h = __builtin_convertvector((floatx2){a, b}, bf16x2);
  return v.u;
}
// async global->LDS, 16B per lane (dest = wave-uniform base + lane*16)
__device__ __forceinline__ void gload16(const void* g, void* l){
  __builtin_amdgcn_global_load_lds((const __attribute__((address_space(1))) unsigned int*)g,
                                   (__attribute__((address_space(3))) unsigned int*)l, 16, 0, 0);
}
__device__ __forceinline__ float redq(float v){   // sum across quads (lanes ^16, ^32)
  v += __shfl_xor(v, 16); v += __shfl_xor(v, 32);
  return v;
}

// ---------------- prep kernels ----------------
__global__ void transpose_w(const float* __restrict__ qkv_w, const float* __restrict__ anchor_w,
                            const float* __restrict__ proj_w,
                            u16* __restrict__ qkvt, u16* __restrict__ anct, u16* __restrict__ projt){
  int id = blockIdx.x*256 + threadIdx.x;
  if (id < 196608){ int k = id / 768, n = id % 768; qkvt[n*256 + k] = f2bf(qkv_w[id]); }
  else if (id < 229376){ int r = id - 196608; int k = r / 128, n = r % 128; anct[n*256 + k] = f2bf(anchor_w[r]); }
  else { int r = id - 229376; int k = r >> 8, n = r & 255; projt[n*256 + k] = f2bf(proj_w[r]); }
}

__global__ void cpb_mlp(const float* __restrict__ tw, const float* __restrict__ ts,
                        const float* __restrict__ w1w, const float* __restrict__ b1w, const float* __restrict__ w2w,
                        const float* __restrict__ w1s1, const float* __restrict__ b1s1, const float* __restrict__ w2s1,
                        const float* __restrict__ w1s2, const float* __restrict__ b1s2, const float* __restrict__ w2s2,
                        float* __restrict__ btw, float* __restrict__ bts1, float* __restrict__ bts2){
  int tag = blockIdx.y;
  const float *tab, *w1, *b1, *w2; float* bt; int T;
  if (tag == 0){ tab = tw; w1 = w1w;  b1 = b1w;  w2 = w2w;  bt = btw;  T = 961; }
  else if (tag == 1){ tab = ts; w1 = w1s1; b1 = b1s1; w2 = w2s1; bt = bts1; T = 1521; }
  else { tab = ts; w1 = w1s2; b1 = b1s2; w2 = w2s2; bt = bts2; T = 1521; }
  __shared__ float sw1[2][512];
  __shared__ float sb1[512];
  __shared__ float sw2[512][4];
  for (int j = threadIdx.x; j < 512; j += 256){
    sw1[0][j] = w1[j]; sw1[1][j] = w1[512 + j]; sb1[j] = b1[j];
    for (int h = 0; h < 4; ++h) sw2[j][h] = w2[j*4 + h];
  }
  __syncthreads();
  int idx = blockIdx.x*256 + threadIdx.x;
  int r = idx >> 2, hh = idx & 3;
  if (r < T){
    float t0 = tab[2*r], t1 = tab[2*r + 1];
    float acc = 0.f;
    for (int j = 0; j < 512; ++j){
      float hj = fmaxf(fmaf(t0, sw1[0][j], fmaf(t1, sw1[1][j], sb1[j])), 0.f);
      acc = fmaf(hj, sw2[j][hh], acc);
    }
    bt[r*4 + hh] = acc;
  }
}

// bias tables pre-folded: (16*sigmoid(v) - off_h) * log2(e), off_h = min(scale_h+16, 80)
// laid out so attention loads are query-contiguous floatx4 per key-quad.
__global__ void bias_gather(const float* __restrict__ btw, const float* __restrict__ bts1,
                            const float* __restrict__ bts2,
                            const int* __restrict__ idxw, const int* __restrict__ idxa2w,
                            const int* __restrict__ idxw2a,
                            const float* __restrict__ lsw, const float* __restrict__ ls1,
                            const float* __restrict__ ls2,
                            float* __restrict__ bw, float* __restrict__ bs1, float* __restrict__ bs2){
  int id = blockIdx.x*256 + threadIdx.x;     // 3 * 262144
  int which = id >> 18;
  int rem = id & 262143;
  int h = rem >> 16, e = rem & 65535;
  const float* bt; const int* ix; float* dst; const float* ls;
  if (which == 0){ bt = btw;  ix = idxw;   dst = bw;  ls = lsw; }
  else if (which == 1){ bt = bts1; ix = idxa2w; dst = bs1; ls = ls1; }
  else { bt = bts2; ix = idxw2a; dst = bs2; ls = ls2; }
  float v = bt[ix[e]*4 + h];
  float scale = exp2f(fminf(ls[h], 4.6051702f) * LOG2E);
  float off = fminf(scale + 16.f, 80.f);
  float sig = 16.f / (1.f + exp2f(-v * LOG2E));
  float out = (sig - off) * LOG2E;
  int idx;
  if (which == 0){
    int q = e >> 8, k = e & 255;
    idx = ((((h*8 + (k>>5))*2 + ((k>>4)&1))*4 + ((k>>2)&3)) << 10) + (q << 2) + (k & 3);
  } else if (which == 1){
    int a = e >> 10, k = e & 1023;
    idx = (((h*64 + (k>>4))*4 + ((k>>2)&3)) << 8) + (a << 2) + (k & 3);
  } else {
    int q = e >> 6, k = e & 63;
    idx = (((h*4 + (k>>4))*4 + ((k>>2)&3)) << 12) + (q << 2) + (k & 3);
  }
  dst[idx] = out;
}

// avgpool + x->bf16 conversion (single pass over x)
__global__ void avgpool(const float* __restrict__ x, u16* __restrict__ xb,
                        u16* __restrict__ pooledb){
  int a = blockIdx.x, c = threadIdx.x;
  int ay = a >> 6, ax = a & 63;
  float acc = 0.f;
#pragma unroll
  for (int dy = 0; dy < 4; ++dy)
#pragma unroll
    for (int dx = 0; dx < 4; ++dx){
      int row = (ay*4 + dy)*256 + ax*4 + dx;
      float v = x[(size_t)row*256 + c];
      xb[(size_t)row*256 + c] = f2bf(v);
      acc += v;
    }
  pooledb[(size_t)a*256 + c] = f2bf(acc * 0.0625f);
}

// ---------------- GEMM (m97-style): C[M,*](bf16) = A[M,256](bf16) @ Bt^T + bias ----------------
// block = 128 rows x 128 cols; both operands DMA-staged, double-buffered (32 KB LDS).
// y -> branch = y/nyb (CW/CS), slice = y%nyb; slice < normSl -> per-(row,32-col head) L2 norm.
__launch_bounds__(256, 2)
__global__ void gemm_bf(const u16* __restrict__ A, const u16* __restrict__ Bt,
                        const float* __restrict__ bias, u16* __restrict__ CW,
                        u16* __restrict__ CS, int Nstr, int nyb, int normSl){
  __shared__ __align__(16) u16 lsA[2][4096];   // [buf][128 rows][32 k]
  __shared__ __align__(16) u16 lsB[2][4096];
  const int tid = threadIdx.x, lane = tid & 63, wv = tid >> 6;
  const int lane15 = lane & 15, quad = lane >> 4;
  const int wr = wv >> 1, wc = wv & 1;
  const int m0 = blockIdx.x * 128;
  const int y = blockIdx.y;
  const int br = y / nyb, sl = y - br*nyb;
  u16* C = br ? CS : CW;
  const int srow = wv*16 + (lane >> 2), sk = (lane & 3)*8;
  const u16* as = A + (size_t)(m0 + srow)*256 + sk;
  const u16* bs = Bt + (size_t)(y*128 + srow)*256 + sk;
  auto stage = [&](int kw, int buf){
    char* dA = (char*)lsA[buf]; char* dB = (char*)lsB[buf];
    gload16(as + kw*32,            dA + wv*1024);
    gload16(as + 64*256 + kw*32,   dA + 4096 + wv*1024);
    gload16(bs + kw*32,            dB + wv*1024);
    gload16(bs + 64*256 + kw*32,   dB + 4096 + wv*1024);
  };
  stage(0, 0);
  floatx4 acc[4][4] = {};
  for (int kw = 0; kw < 8; ++kw){
    __syncthreads();
    if (kw < 7) stage(kw + 1, (kw + 1) & 1);
    const char* Ac = (const char*)lsA[kw & 1];
    const char* Bc = (const char*)lsB[kw & 1];
    short8 a[4], b[4];
#pragma unroll
    for (int i = 0; i < 4; ++i)
      a[i] = *(const short8*)(Ac + (wr*64 + i*16 + lane15)*64 + quad*16);
#pragma unroll
    for (int j = 0; j < 4; ++j)
      b[j] = *(const short8*)(Bc + (wc*64 + j*16 + lane15)*64 + quad*16);
#pragma unroll
    for (int i = 0; i < 4; ++i)
#pragma unroll
      for (int j = 0; j < 4; ++j)
        acc[i][j] = __builtin_amdgcn_mfma_f32_16x16x32_bf16(b[j], a[i], acc[i][j], 0, 0, 0);
  }
  // swapped mapping: lane15 -> row, quad*4+r -> col
#pragma unroll
  for (int j = 0; j < 4; ++j){
    floatx4 bz = *(const floatx4*)(bias + y*128 + wc*64 + j*16 + quad*4);
#pragma unroll
    for (int i = 0; i < 4; ++i) acc[i][j] += bz;
  }
  if (sl < normSl){
#pragma unroll
    for (int i = 0; i < 4; ++i)
#pragma unroll
      for (int jp = 0; jp < 2; ++jp){
        floatx4 s2 = acc[i][jp*2]*acc[i][jp*2] + acc[i][jp*2+1]*acc[i][jp*2+1];
        float ss = (s2.x + s2.y) + (s2.z + s2.w);
        ss = redq(ss);
        float inv = 1.f / fmaxf(sqrtf(ss), 1e-12f);
        acc[i][jp*2]   *= inv;
        acc[i][jp*2+1] *= inv;
      }
  }
#pragma unroll
  for (int i = 0; i < 4; ++i){
    int row = m0 + wr*64 + i*16 + lane15;
#pragma unroll
    for (int j = 0; j < 4; ++j){
      int colb = sl*128 + wc*64 + j*16 + quad*4;
      uintx2 w;
      w.x = pk2(acc[i][j][0], acc[i][j][1]);
      w.y = pk2(acc[i][j][2], acc[i][j][3]);
      *(uintx2*)(C + (size_t)row*Nstr + colb) = w;
    }
  }
}

// ---------------- proj GEMM: Cout[M,256](f32) = Ab[M,256](bf16) @ Bt^T + bias ----------------
__launch_bounds__(256, 2)
__global__ void gemm_proj(const u16* __restrict__ Ab, const u16* __restrict__ Bt,
                          const float* __restrict__ bias, float* __restrict__ Cout){
  __shared__ __align__(16) u16 lsA[2][4096];   // [buf][128 rows][32 k]
  __shared__ __align__(16) u16 lsB[2][8192];   // [buf][256 rows][32 k]
  const int tid = threadIdx.x, lane = tid & 63, wv = tid >> 6;
  const int lane15 = lane & 15, quad = lane >> 4;
  const int wr = wv >> 1, wc = wv & 1;     // wave = 64 rows x 128 cols
  const int m0 = blockIdx.x * 128;
  const int srow = wv*16 + (lane >> 2), sk = (lane & 3)*8;
  const u16* as = Ab + (size_t)(m0 + srow)*256 + sk;
  const u16* bs = Bt + (size_t)srow*256 + sk;
  auto stage = [&](int kw, int buf){
    char* dA = (char*)lsA[buf]; char* dB = (char*)lsB[buf];
    gload16(as + kw*32,             dA + wv*1024);
    gload16(as + 64*256 + kw*32,    dA + 4096  + wv*1024);
    gload16(bs + kw*32,             dB + wv*1024);
    gload16(bs + 64*256 + kw*32,    dB + 4096  + wv*1024);
    gload16(bs + 128*256 + kw*32,   dB + 8192  + wv*1024);
    gload16(bs + 192*256 + kw*32,   dB + 12288 + wv*1024);
  };
  stage(0, 0);
  floatx4 acc[4][8] = {};
  for (int kw = 0; kw < 8; ++kw){
    __syncthreads();
    if (kw < 7) stage(kw + 1, (kw + 1) & 1);
    const char* Ac = (const char*)lsA[kw & 1];
    const char* Bc = (const char*)lsB[kw & 1];
    short8 a[4], b[8];
#pragma unroll
    for (int i = 0; i < 4; ++i)
      a[i] = *(const short8*)(Ac + (wr*64 + i*16 + lane15)*64 + quad*16);
#pragma unroll
    for (int j = 0; j < 8; ++j)
      b[j] = *(const short8*)(Bc + (wc*128 + j*16 + lane15)*64 + quad*16);
#pragma unroll
    for (int i = 0; i < 4; ++i)
#pragma unroll
      for (int j = 0; j < 8; ++j)
        acc[i][j] = __builtin_amdgcn_mfma_f32_16x16x32_bf16(b[j], a[i], acc[i][j], 0, 0, 0);
  }
#pragma unroll
  for (int i = 0; i < 4; ++i){
    int row = m0 + wr*64 + i*16 + lane15;
#pragma unroll
    for (int j = 0; j < 8; ++j){
      int colb = wc*128 + j*16 + quad*4;
      floatx4 bz = *(const floatx4*)(bias + colb);
      floatx4 o = acc[i][j] + bz;
      *(floatx4*)(Cout + (size_t)row*256 + colb) = o;
    }
  }
}

// ---------------- window attention (S^T formulation), full image ----------------
// qkvh: [65536][384] bf16, Qn[0,128) Kn[128,256) V[256,384); grid (256 windows, 4 heads)
// VT oct stride padded 256->264 u16: write banks (4*oct + e/2) cover all 32 -> conflict-free.
__launch_bounds__(256, 3)
__global__ void win_attn(const u16* __restrict__ qkvh, const float* __restrict__ lsw,
                         const float* __restrict__ biasw, u16* __restrict__ outm){
  __shared__ __align__(16) u16 sm[24832];   // K[0,8192) Q[8192,16384)->P  VT[16384, 16384+32*264)
  const int tid = threadIdx.x, lane = tid & 63, wv = tid >> 6;
  const int lane15 = lane & 15, quad = lane >> 4;
  const int h = blockIdx.y;
  const int wyl = blockIdx.x >> 4, wx = blockIdx.x & 15;
  u16* Ks = sm;
  u16* Qs = sm + 8192;
  u16* VT = sm + 16384;
  { // stage: DMA Q,K (pre-normalized) into k-outer [kq][256 tok][8]; V scalar-transposed
    int tok = wv*64 + lane;
    int row = (wyl*16 + (tok >> 4))*256 + wx*16 + (tok & 15);
    const char* src = (const char*)qkvh + (size_t)row*768 + h*64;
#pragma unroll
    for (int kq = 0; kq < 4; ++kq){
      gload16(src + kq*16,        (char*)Qs + wv*1024 + kq*4096);
      gload16(src + 256 + kq*16,  (char*)Ks + wv*1024 + kq*4096);
    }
    int vrow = (wyl*16 + (tid >> 4))*256 + wx*16 + (tid & 15);
    const uintx4* vp = (const uintx4*)((const char*)qkvh + (size_t)vrow*768 + 512 + h*64);
    uintx4 v0 = vp[0], v1 = vp[1], v2 = vp[2], v3 = vp[3];
    unsigned int w[16] = {v0.x,v0.y,v0.z,v0.w, v1.x,v1.y,v1.z,v1.w,
                          v2.x,v2.y,v2.z,v2.w, v3.x,v3.y,v3.z,v3.w};
    u16* vd = VT + (tid >> 3)*264 + (tid & 7);
#pragma unroll
    for (int c = 0; c < 16; ++c){
      vd[(c*2)*8]   = (u16)(w[c] & 0xffffu);
      vd[(c*2+1)*8] = (u16)(w[c] >> 16);
    }
  }
  __syncthreads();
  short8 qf[4];                 // wave owns queries wv*64 .. +63 (B-operand)
#pragma unroll
  for (int j = 0; j < 4; ++j)
    qf[j] = *(const short8*)(Qs + quad*2048 + (wv*64 + j*16 + lane15)*8);
  __syncthreads();              // all Q reads done before P overwrites

  float scale = exp2f(fminf(lsw[h], 4.6051702f) * LOG2E) * LOG2E;
  u16* Pw = Qs + wv*2048;       // per-wave P^T: [4 key-octs][64 queries][8]
  const floatx4 zf4 = {0.f, 0.f, 0.f, 0.f};
  floatx4 accO[2][4] = {};      // O^T: [d-tile][query-tile]
  float lsum[4] = {};

  for (int kc = 0; kc < 8; ++kc){      // 32 keys per chunk
    floatx4 bia[2][4];
#pragma unroll
    for (int i = 0; i < 2; ++i)
#pragma unroll
      for (int j = 0; j < 4; ++j)
        bia[i][j] = *(const floatx4*)(biasw + ((((h*8 + kc)*2 + i)*4 + quad) << 10)
                                            + ((wv*64 + j*16 + lane15) << 2));
    short8 kf[2];
#pragma unroll
    for (int i = 0; i < 2; ++i)
      kf[i] = *(const short8*)(Ks + quad*2048 + (kc*32 + i*16 + lane15)*8);
#pragma unroll
    for (int i = 0; i < 2; ++i)
#pragma unroll
      for (int j = 0; j < 4; ++j){
        floatx4 sv = __builtin_amdgcn_mfma_f32_16x16x32_bf16(kf[i], qf[j], zf4, 0, 0, 0);
        float p0 = exp2f(fmaf(sv[0], scale, bia[i][j][0]));
        float p1 = exp2f(fmaf(sv[1], scale, bia[i][j][1]));
        float p2 = exp2f(fmaf(sv[2], scale, bia[i][j][2]));
        float p3 = exp2f(fmaf(sv[3], scale, bia[i][j][3]));
        lsum[j] += (p0 + p1) + (p2 + p3);
        uintx2 w; w.x = pk2(p0, p1); w.y = pk2(p2, p3);
        *(uintx2*)(Pw + (i*2 + (quad>>1))*512 + (j*16 + lane15)*8 + (quad&1)*4) = w;
      }
    asm volatile("s_waitcnt lgkmcnt(0)" ::: "memory");
    short8 ptf[4], vtf[2];
#pragma unroll
    for (int j = 0; j < 4; ++j)
      ptf[j] = *(const short8*)(Pw + quad*512 + (j*16 + lane15)*8);
#pragma unroll
    for (int m = 0; m < 2; ++m)
      vtf[m] = *(const short8*)(VT + (kc*4 + quad)*264 + (m*16 + lane15)*8);
#pragma unroll
    for (int m = 0; m < 2; ++m)
#pragma unroll
      for (int j = 0; j < 4; ++j)
        accO[m][j] = __builtin_amdgcn_mfma_f32_16x16x32_bf16(vtf[m], ptf[j], accO[m][j], 0, 0, 0);
  }
  float linv[4];
#pragma unroll
  for (int j = 0; j < 4; ++j) linv[j] = 1.f / redq(lsum[j]);
#pragma unroll
  for (int m = 0; m < 2; ++m)
#pragma unroll
    for (int j = 0; j < 4; ++j){
      int tok = wv*64 + j*16 + lane15;
      int py = wyl*16 + (tok >> 4), px = wx*16 + (tok & 15);
      floatx4 o = accO[m][j] * linv[j];
      uintx2 w; w.x = pk2(o[0], o[1]); w.y = pk2(o[2], o[3]);
      *(uintx2*)(outm + (size_t)(py*256 + px)*256 + h*32 + m*16 + quad*4) = w;
    }
}

// ---------------- stripe phase 1: xm partials (key-split), full image ----------------
// grid (64 stripes, 4 heads, 2 key-halves). VT: oct stride 272, dh offset 136 (conflict-free).
__launch_bounds__(256, 3)
__global__ void stripe_xm(const u16* __restrict__ qkvh, const u16* __restrict__ anchor,
                          const float* __restrict__ ls1, const float* __restrict__ bias1,
                          float* __restrict__ gl1, u16* __restrict__ gO){
  __shared__ __align__(16) u16 sm[22784];  // ANC[0,2048) KC0[2048,6144) KC1[6144,10240) VT[10240,14592) P1T[14592,22784)
  const int tid = threadIdx.x, lane = tid & 63, wv = tid >> 6;
  const int lane15 = lane & 15, quad = lane >> 4;
  const int s = blockIdx.x, h = blockIdx.y, kb = blockIdx.z;
  const int syl = s >> 3, sx = s & 7;
  u16* ANC = sm; u16* VT = sm + 10240; u16* P1T = sm + 14592;
  if (wv == 0){   // anchors pre-normalized in anch
    int ay = syl*8 + (lane >> 3), ax = sx*8 + (lane & 7);
    const char* asrc = (const char*)anchor + (size_t)(ay*64 + ax)*256 + h*64;
#pragma unroll
    for (int kq = 0; kq < 4; ++kq)
      gload16(asrc + kq*16, (char*)ANC + kq*1024);
  }
  auto stageK = [&](int kc){
    int kkb = kb*512 + kc*128;
    char* KC = (char*)sm + 4096 + (kc & 1)*8192;
#pragma unroll
    for (int hf = 0; hf < 2; ++hf){
      int tok = kkb + hf*64 + lane;
      int row = (syl*32 + (tok >> 5))*256 + sx*32 + (tok & 31);
      gload16((const char*)qkvh + (size_t)row*768 + 256 + h*64 + wv*16,
              KC + wv*2048 + hf*1024);
    }
  };
  stageK(0);
  float scale1 = exp2f(fminf(ls1[h], 4.6051702f) * LOG2E) * LOG2E;
  const floatx4 zf4 = {0.f, 0.f, 0.f, 0.f};
  floatx4 accO1[2] = {};
  float l1 = 0.f;
  for (int kc = 0; kc < 4; ++kc){
    int kkb = kb*512 + kc*128;
    { // stage V(kc): token tid>>1, d-half tid&1; direct u16 transpose
      int tok_l = tid >> 1, dh = tid & 1;
      int tok = kkb + tok_l;
      int row = (syl*32 + (tok >> 5))*256 + sx*32 + (tok & 31);
      const uintx4* vp = (const uintx4*)((const char*)qkvh + (size_t)row*768 + 512 + h*64 + dh*32);
      uintx4 v0 = vp[0], v1 = vp[1];
      unsigned int w[8] = {v0.x,v0.y,v0.z,v0.w, v1.x,v1.y,v1.z,v1.w};
      u16* vd = VT + (tok_l >> 3)*272 + dh*136 + (tok_l & 7);
#pragma unroll
      for (int c = 0; c < 8; ++c){
        vd[(c*2)*8]   = (u16)(w[c] & 0xffffu);
        vd[(c*2+1)*8] = (u16)(w[c] >> 16);
      }
    }
    __syncthreads();                       // VT visible; KC(kc) DMA drained; ANC ready
    if (kc < 3) stageK(kc + 1);            // overlaps compute, drains at end barrier
    const u16* KC = sm + 2048 + (kc & 1)*4096;
    short8 ancf = *(const short8*)(ANC + quad*512 + (wv*16 + lane15)*8);
    floatx4 bia[8];
#pragma unroll
    for (int i = 0; i < 8; ++i)
      bia[i] = *(const floatx4*)(bias1 + (((h*64 + kb*32 + kc*8 + i)*4 + quad) << 8)
                                       + ((wv*16 + lane15) << 2));
#pragma unroll
    for (int i = 0; i < 8; ++i){
      short8 kf = *(const short8*)(KC + quad*1024 + (i*16 + lane15)*8);
      floatx4 sv = __builtin_amdgcn_mfma_f32_16x16x32_bf16(kf, ancf, zf4, 0, 0, 0);
      float p0 = exp2f(fmaf(sv[0], scale1, bia[i][0]));
      float p1 = exp2f(fmaf(sv[1], scale1, bia[i][1]));
      float p2 = exp2f(fmaf(sv[2], scale1, bia[i][2]));
      float p3 = exp2f(fmaf(sv[3], scale1, bia[i][3]));
      l1 += (p0 + p1) + (p2 + p3);
      uintx2 w; w.x = pk2(p0, p1); w.y = pk2(p2, p3);
      *(uintx2*)(P1T + (i*2 + (quad>>1))*512 + (wv*16 + lane15)*8 + (quad&1)*4) = w;
    }
    asm volatile("s_waitcnt lgkmcnt(0)" ::: "memory");
#pragma unroll
    for (int ks = 0; ks < 4; ++ks){
      short8 ptf = *(const short8*)(P1T + (ks*4 + quad)*512 + (wv*16 + lane15)*8);
#pragma unroll
      for (int m = 0; m < 2; ++m){
        short8 vtf = *(const short8*)(VT + (ks*4 + quad)*272 + m*136 + lane15*8);
        accO1[m] = __builtin_amdgcn_mfma_f32_16x16x32_bf16(vtf, ptf, accO1[m], 0, 0, 0);
      }
    }
    __syncthreads();   // protect VT/P1T before next-iter staging
  }
  l1 = redq(l1);
  int ent = (s*4 + h)*2 + kb;
  if (quad == 0) gl1[ent*64 + wv*16 + lane15] = l1;
#pragma unroll
  for (int m = 0; m < 2; ++m){
    uintx2 w; w.x = pk2(accO1[m][0], accO1[m][1]); w.y = pk2(accO1[m][2], accO1[m][3]);
    *(uintx2*)(gO + (size_t)ent*2048 + (wv*16 + lane15)*32 + m*16 + quad*4) = w;
  }
}

// ---------------- stripe phase 2: xs, full image ----------------
// grid (64 stripes * 4 query-chunks, 4 heads)
__launch_bounds__(256, 3)
__global__ void stripe_xs(const u16* __restrict__ qkvh, const u16* __restrict__ anchor,
                          const float* __restrict__ ls2, const float* __restrict__ bias2,
                          const float* __restrict__ gl1, const u16* __restrict__ gO,
                          u16* __restrict__ outm){
  __shared__ __align__(16) u16 sm[20480]; // ANC[0,2048) XMT[2048,4096) QW[4096+wv*2048) P2T[12288+wv*2048)
  const int tid = threadIdx.x, lane = tid & 63, wv = tid >> 6;
  const int lane15 = lane & 15, quad = lane >> 4;
  const int s = blockIdx.x >> 2, qc = blockIdx.x & 3, h = blockIdx.y;
  const int syl = s >> 3, sx = s & 7;
  u16* ANC = sm;
  u16* XMT = sm + 2048;
  u16* QW  = sm + 4096 + wv*2048;
  u16* P2T = sm + 12288 + wv*2048;
  if (wv == 0){
    int ay = syl*8 + (lane >> 3), ax = sx*8 + (lane & 7);
    const char* asrc = (const char*)anchor + (size_t)(ay*64 + ax)*256 + h*64;
#pragma unroll
    for (int kq = 0; kq < 4; ++kq)
      gload16(asrc + kq*16, (char*)ANC + kq*1024);
  }
  { // combine xm partials -> XMT [anchor-oct][d 32][8] bf16
    int a = tid >> 2, db = (tid & 3)*8;
    int e0 = (s*4 + h)*2;
    float inv = 1.f / (gl1[e0*64 + a] + gl1[(e0 + 1)*64 + a]);
    uintx4 u0 = *(const uintx4*)(gO + (size_t)e0*2048 + a*32 + db);
    uintx4 u1 = *(const uintx4*)(gO + (size_t)(e0 + 1)*2048 + a*32 + db);
    unsigned int w0[4] = {u0.x, u0.y, u0.z, u0.w};
    unsigned int w1[4] = {u1.x, u1.y, u1.z, u1.w};
#pragma unroll
    for (int c = 0; c < 4; ++c){
      float a0 = bf2f((u16)(w0[c] & 0xffffu)) + bf2f((u16)(w1[c] & 0xffffu));
      float a1 = bf2f((u16)(w0[c] >> 16))     + bf2f((u16)(w1[c] >> 16));
      XMT[(a >> 3)*256 + (db + c*2)*8     + (a & 7)] = f2bf(a0 * inv);
      XMT[(a >> 3)*256 + (db + c*2 + 1)*8 + (a & 7)] = f2bf(a1 * inv);
    }
  }
  int tq = qc*256 + wv*64;     // query base within stripe (wave owns 64)
  { // DMA stage this wave's 64 queries (pre-normalized)
    int tok = tq + lane;
    int row = (syl*32 + (tok >> 5))*256 + sx*32 + (tok & 31);
    const char* src = (const char*)qkvh + (size_t)row*768 + h*64;
#pragma unroll
    for (int kq = 0; kq < 4; ++kq)
      gload16(src + kq*16, (char*)QW + kq*1024);
  }
  __syncthreads();
  short8 qf2[4];
#pragma unroll
  for (int j = 0; j < 4; ++j)
    qf2[j] = *(const short8*)(QW + quad*512 + (j*16 + lane15)*8);
  float scale2 = exp2f(fminf(ls2[h], 4.6051702f) * LOG2E) * LOG2E;
  const floatx4 zf4 = {0.f, 0.f, 0.f, 0.f};
  floatx4 accO2[2][4] = {};
  float l2[4] = {};
#pragma unroll
  for (int c = 0; c < 2; ++c){      // 2 anchor chunks of 32
    floatx4 bia[2][4];
#pragma unroll
    for (int i = 0; i < 2; ++i)
#pragma unroll
      for (int j = 0; j < 4; ++j)
        bia[i][j] = *(const floatx4*)(bias2 + ((((h*4 + c*2 + i)*4 + quad) << 12)
                                             + ((tq + j*16 + lane15) << 2)));
    short8 af[2];
#pragma unroll
    for (int i = 0; i < 2; ++i)
      af[i] = *(const short8*)(ANC + quad*512 + (c*32 + i*16 + lane15)*8);
#pragma unroll
    for (int i = 0; i < 2; ++i)
#pragma unroll
      for (int j = 0; j < 4; ++j){
        floatx4 sv = __builtin_amdgcn_mfma_f32_16x16x32_bf16(af[i], qf2[j], zf4, 0, 0, 0);
        float p0 = exp2f(fmaf(sv[0], scale2, bia[i][j][0]));
        float p1 = exp2f(fmaf(sv[1], scale2, bia[i][j][1]));
        float p2 = exp2f(fmaf(sv[2], scale2, bia[i][j][2]));
        float p3 = exp2f(fmaf(sv[3], scale2, bia[i][j][3]));
        l2[j] += (p0 + p1) + (p2 + p3);
        uintx2 w; w.x = pk2(p0, p1); w.y = pk2(p2, p3);
        *(uintx2*)(P2T + (i*2 + (quad>>1))*512 + (j*16 + lane15)*8 + (quad&1)*4) = w;
      }
    asm volatile("s_waitcnt lgkmcnt(0)" ::: "memory");
    short8 ptf[4], xmf[2];
#pragma unroll
    for (int j = 0; j < 4; ++j)
      ptf[j] = *(const short8*)(P2T + quad*512 + (j*16 + lane15)*8);
#pragma unroll
    for (int m = 0; m < 2; ++m)
      xmf[m] = *(const short8*)(XMT + (c*4 + quad)*256 + (m*16 + lane15)*8);
#pragma unroll
    for (int m = 0; m < 2; ++m)
#pragma unroll
      for (int j = 0; j < 4; ++j)
        accO2[m][j] = __builtin_amdgcn_mfma_f32_16x16x32_bf16(xmf[m], ptf[j], accO2[m][j], 0, 0, 0);
  }
  float linv[4];
#pragma unroll
  for (int j = 0; j < 4; ++j) linv[j] = 1.f / redq(l2[j]);
#pragma unroll
  for (int m = 0; m < 2; ++m)
#pragma unroll
    for (int j = 0; j < 4; ++j){
      int tok = tq + j*16 + lane15;
      int py = syl*32 + (tok >> 5), px = sx*32 + (tok & 31);
      floatx4 o = accO2[m][j] * linv[j];
      uintx2 w; w.x = pk2(o[0], o[1]); w.y = pk2(o[2], o[3]);
      *(uintx2*)(outm + (size_t)(py*256 + px)*256 + 128 + h*32 + m*16 + quad*4) = w;
    }
}

// ---------------- launch ----------------
extern "C" void kernel_launch(void* const* d_in, const int* in_sizes, int n_in,
                              void* d_out, int out_size, void* d_ws, size_t ws_size,
                              hipStream_t stream) {
  (void)in_sizes; (void)n_in; (void)out_size; (void)ws_size;
  const float* x        = (const float*)d_in[0];
  const float* qkv_w    = (const float*)d_in[1];
  const float* qkv_b    = (const float*)d_in[2];
  const float* anchor_w = (const float*)d_in[3];
  const float* anchor_b = (const float*)d_in[4];
  const float* ls_w     = (const float*)d_in[5];
  const float* w1_w     = (const float*)d_in[6];
  const float* b1_w     = (const float*)d_in[7];
  const float* w2_w     = (const float*)d_in[8];
  const float* ls_s1    = (const float*)d_in[9];
  const float* w1_s1    = (const float*)d_in[10];
  const float* b1_s1    = (const float*)d_in[11];
  const float* w2_s1    = (const float*)d_in[12];
  const float* ls_s2    = (const float*)d_in[13];
  const float* w1_s2    = (const float*)d_in[14];
  const float* b1_s2    = (const float*)d_in[15];
  const float* w2_s2    = (const float*)d_in[16];
  const float* proj_w   = (const float*)d_in[17];
  const float* proj_b   = (const float*)d_in[18];
  const float* table_w  = (const float*)d_in[19];
  const float* table_s  = (const float*)d_in[20];
  const int* index_w   = (const int*)d_in[21];
  const int* index_a2w = (const int*)d_in[22];
  const int* index_w2a = (const int*)d_in[23];

  // ---- workspace layout (~177 MB; ws = 256 MiB per poison-fill WRITE_SIZE) ----
  char* ws = (char*)d_ws;
  u16*   qkvhW  = (u16*)(ws + 0);                  // 65536*384 bf16 = 50331648 B
  u16*   qkvhS  = (u16*)(ws + 50331648);           // 65536*384 bf16
  u16*   mergedb= (u16*)(ws + 100663296);          // 65536*256 bf16 = 33554432 B
  u16*   xb     = (u16*)(ws + 134217728);          // 65536*256 bf16 = 33554432 B
  u16*   pooledb= (u16*)(ws + 167772160);          // 4096*256 bf16 = 2 MB
  u16*   anch   = (u16*)(ws + 169869312);          // 4096*128 bf16 = 1 MB
  u16*   qkvt   = (u16*)(ws + 170917888);          // 768*256 bf16
  u16*   anct   = (u16*)(ws + 171311104);          // 128*256 bf16
  u16*   projt  = (u16*)(ws + 171376640);          // 256*256 bf16
  float* btw    = (float*)(ws + 171507712);
  float* bts1   = (float*)(ws + 171524096);
  float* bts2   = (float*)(ws + 171548672);
  float* biasw  = (float*)(ws + 171573248);        // 4*65536 f32 = 1 MB
  float* bias1  = (float*)(ws + 172621824);        // 1 MB
  float* bias2  = (float*)(ws + 173670400);        // 1 MB
  float* gl1    = (float*)(ws + 174718976);        // 512*64 f32 = 128 KB
  u16*   gO     = (u16*)(ws + 174850048);          // 512*2048 bf16 = 2 MB (end 176947200)

  transpose_w<<<1152, 256, 0, stream>>>(qkv_w, anchor_w, proj_w, qkvt, anct, projt);
  cpb_mlp<<<dim3(24, 3), 256, 0, stream>>>(table_w, table_s,
                                           w1_w, b1_w, w2_w,
                                           w1_s1, b1_s1, w2_s1,
                                           w1_s2, b1_s2, w2_s2,
                                           btw, bts1, bts2);
  bias_gather<<<3072, 256, 0, stream>>>(btw, bts1, bts2, index_w, index_a2w, index_w2a,
                                        ls_w, ls_s1, ls_s2, biasw, bias1, bias2);
  avgpool<<<4096, 256, 0, stream>>>(x, xb, pooledb);
  // anchor projection (normalized)
  gemm_bf<<<dim3(32, 1), 256, 0, stream>>>(pooledb, anct, anchor_b, anch, anch, 128, 1, 1);
  // both qkv branches in one launch: y 0..2 -> W slices (Qn,Kn,V), y 3..5 -> S slices
  gemm_bf<<<dim3(512, 6), 256, 0, stream>>>(xb, qkvt, qkv_b, qkvhW, qkvhS, 384, 3, 2);
  win_attn<<<dim3(256, 4), 256, 0, stream>>>(qkvhW, ls_w, biasw, mergedb);
  stripe_xm<<<dim3(64, 4, 2), 256, 0, stream>>>(qkvhS, anch, ls_s1, bias1, gl1, gO);
  stripe_xs<<<dim3(256, 4), 256, 0, stream>>>(qkvhS, anch, ls_s2, bias2, gl1, gO, mergedb);
  // output projection: bf16 merged -> f32 d_out
  gemm_proj<<<512, 256, 0, stream>>>(mergedb, projt, proj_b, (float*)d_out);
}

// Round 7
// 349.647 us; speedup vs baseline: 1.2109x; 1.0040x over previous
//
#include <hip/hip_runtime.h>
#include <cstdint>
#include <cstddef>

typedef unsigned short u16;
typedef __attribute__((ext_vector_type(8))) short short8;
typedef __attribute__((ext_vector_type(4))) float floatx4;
typedef __attribute__((ext_vector_type(2))) float floatx2;
typedef __attribute__((ext_vector_type(4))) unsigned int uintx4;
typedef __attribute__((ext_vector_type(2))) unsigned int uintx2;
typedef __attribute__((ext_vector_type(2))) __bf16 bf16x2;

#define LOG2E 1.44269504f

__device__ __forceinline__ float bf2f(u16 u){
  union { unsigned int i; float f; } v; v.i = ((unsigned int)u) << 16; return v.f;
}
__device__ __forceinline__ u16 f2bf(float f){
  union { __bf16 b; u16 u; } v; v.b = (__bf16)f; return v.u;
}
// packed f32x2 -> bf16x2 (v_cvt_pk_bf16_f32, RNE)
__device__ __forceinline__ unsigned int pk2(float a, float b){
  union { bf16x2 h; unsigned int u; } v;
  v.h = __builtin_convertvector((floatx2){a, b}, bf16x2);
  return v.u;
}
// async global->LDS, 16B per lane (dest = wave-uniform base + lane*16)
__device__ __forceinline__ void gload16(const void* g, void* l){
  __builtin_amdgcn_global_load_lds((const __attribute__((address_space(1))) unsigned int*)g,
                                   (__attribute__((address_space(3))) unsigned int*)l, 16, 0, 0);
}
__device__ __forceinline__ float redq(float v){   // sum across quads (lanes ^16, ^32)
  v += __shfl_xor(v, 16); v += __shfl_xor(v, 32);
  return v;
}

// ---------------- prep_all: transpose_w (0..1151) | cpb_mlp (1152..1223) | avgpool (1224..5319) ----
__global__ void prep_all(const float* __restrict__ x,
                         const float* __restrict__ qkv_w, const float* __restrict__ anchor_w,
                         const float* __restrict__ proj_w,
                         const float* __restrict__ tw, const float* __restrict__ ts,
                         const float* __restrict__ w1w, const float* __restrict__ b1w, const float* __restrict__ w2w,
                         const float* __restrict__ w1s1, const float* __restrict__ b1s1, const float* __restrict__ w2s1,
                         const float* __restrict__ w1s2, const float* __restrict__ b1s2, const float* __restrict__ w2s2,
                         u16* __restrict__ qkvt, u16* __restrict__ anct, u16* __restrict__ projt,
                         float* __restrict__ btw, float* __restrict__ bts1, float* __restrict__ bts2,
                         u16* __restrict__ xb, u16* __restrict__ pooledb){
  __shared__ float sw1[2][512];
  __shared__ float sb1[512];
  __shared__ float sw2[512][4];
  const int bid = blockIdx.x;
  if (bid < 1152){
    int id = bid*256 + threadIdx.x;
    if (id < 196608){ int k = id / 768, n = id % 768; qkvt[n*256 + k] = f2bf(qkv_w[id]); }
    else if (id < 229376){ int r = id - 196608; int k = r / 128, n = r % 128; anct[n*256 + k] = f2bf(anchor_w[r]); }
    else { int r = id - 229376; int k = r >> 8, n = r & 255; projt[n*256 + k] = f2bf(proj_w[r]); }
  } else if (bid < 1224){
    int cb = bid - 1152;
    int tag = cb / 24, xb24 = cb % 24;
    const float *tab, *w1, *b1, *w2; float* bt; int T;
    if (tag == 0){ tab = tw; w1 = w1w;  b1 = b1w;  w2 = w2w;  bt = btw;  T = 961; }
    else if (tag == 1){ tab = ts; w1 = w1s1; b1 = b1s1; w2 = w2s1; bt = bts1; T = 1521; }
    else { tab = ts; w1 = w1s2; b1 = b1s2; w2 = w2s2; bt = bts2; T = 1521; }
    for (int j = threadIdx.x; j < 512; j += 256){
      sw1[0][j] = w1[j]; sw1[1][j] = w1[512 + j]; sb1[j] = b1[j];
      for (int h = 0; h < 4; ++h) sw2[j][h] = w2[j*4 + h];
    }
    __syncthreads();
    int idx = xb24*256 + threadIdx.x;
    int r = idx >> 2, hh = idx & 3;
    if (r < T){
      float t0 = tab[2*r], t1 = tab[2*r + 1];
      float acc = 0.f;
      for (int j = 0; j < 512; ++j){
        float hj = fmaxf(fmaf(t0, sw1[0][j], fmaf(t1, sw1[1][j], sb1[j])), 0.f);
        acc = fmaf(hj, sw2[j][hh], acc);
      }
      bt[r*4 + hh] = acc;
    }
  } else {
    int a = bid - 1224, c = threadIdx.x;
    int ay = a >> 6, ax = a & 63;
    float acc = 0.f;
#pragma unroll
    for (int dy = 0; dy < 4; ++dy)
#pragma unroll
      for (int dx = 0; dx < 4; ++dx){
        int row = (ay*4 + dy)*256 + ax*4 + dx;
        float v = x[(size_t)row*256 + c];
        xb[(size_t)row*256 + c] = f2bf(v);
        acc += v;
      }
    pooledb[(size_t)a*256 + c] = f2bf(acc * 0.0625f);
  }
}

// bias tables pre-folded: (16*sigmoid(v) - off_h) * log2(e), off_h = min(scale_h+16, 80)
// laid out so attention loads are query-contiguous floatx4 per key-quad.
__global__ void bias_gather(const float* __restrict__ btw, const float* __restrict__ bts1,
                            const float* __restrict__ bts2,
                            const int* __restrict__ idxw, const int* __restrict__ idxa2w,
                            const int* __restrict__ idxw2a,
                            const float* __restrict__ lsw, const float* __restrict__ ls1,
                            const float* __restrict__ ls2,
                            float* __restrict__ bw, float* __restrict__ bs1, float* __restrict__ bs2){
  int id = blockIdx.x*256 + threadIdx.x;     // 3 * 262144
  int which = id >> 18;
  int rem = id & 262143;
  int h = rem >> 16, e = rem & 65535;
  const float* bt; const int* ix; float* dst; const float* ls;
  if (which == 0){ bt = btw;  ix = idxw;   dst = bw;  ls = lsw; }
  else if (which == 1){ bt = bts1; ix = idxa2w; dst = bs1; ls = ls1; }
  else { bt = bts2; ix = idxw2a; dst = bs2; ls = ls2; }
  float v = bt[ix[e]*4 + h];
  float scale = exp2f(fminf(ls[h], 4.6051702f) * LOG2E);
  float off = fminf(scale + 16.f, 80.f);
  float sig = 16.f / (1.f + exp2f(-v * LOG2E));
  float out = (sig - off) * LOG2E;
  int idx;
  if (which == 0){
    int q = e >> 8, k = e & 255;
    idx = ((((h*8 + (k>>5))*2 + ((k>>4)&1))*4 + ((k>>2)&3)) << 10) + (q << 2) + (k & 3);
  } else if (which == 1){
    int a = e >> 10, k = e & 1023;
    idx = (((h*64 + (k>>4))*4 + ((k>>2)&3)) << 8) + (a << 2) + (k & 3);
  } else {
    int q = e >> 6, k = e & 63;
    idx = (((h*4 + (k>>4))*4 + ((k>>2)&3)) << 12) + (q << 2) + (k & 3);
  }
  dst[idx] = out;
}

// ---------------- unified GEMM: bf16 A[*,256] @ Bt^T + bias -> bf16 C ----------------
// y<6: qkv (A=xb, branch y/3, slice y%3, norm if slice<2). y==6: anchor (A=pooledb, x<32).
// Both operands DMA-staged dbuf; epilogue via padded LDS C-tile -> full-line global stores.
__launch_bounds__(256, 4)
__global__ void gemm_all(const u16* __restrict__ xb, const u16* __restrict__ pooledb,
                         const u16* __restrict__ qkvt, const u16* __restrict__ anct,
                         const float* __restrict__ qkv_b, const float* __restrict__ anchor_b,
                         u16* __restrict__ CW, u16* __restrict__ CS, u16* __restrict__ anch){
  __shared__ __align__(16) u16 smem[17408];   // staging 32KB: A0@0 A1@8K B0@16K B1@24K (bytes); ctile 128x136 u16
  const int tid = threadIdx.x, lane = tid & 63, wv = tid >> 6;
  const int lane15 = lane & 15, quad = lane >> 4;
  const int wr = wv >> 1, wc = wv & 1;
  const int y = blockIdx.y;
  const int m0 = blockIdx.x * 128;
  const u16 *Ap, *Btp; const float* bp; u16* C; int Nst, sl, nrm;
  if (y == 6){
    if (blockIdx.x >= 32) return;
    Ap = pooledb; Btp = anct; bp = anchor_b; C = anch; Nst = 128; sl = 0; nrm = 1;
  } else {
    Ap = xb; Btp = qkvt + (size_t)y*128*256; bp = qkv_b + y*128;
    C = (y < 3) ? CW : CS; Nst = 384; sl = y % 3; nrm = (sl < 2);
  }
  char* base = (char*)smem;
  const int srow = wv*16 + (lane >> 2), sk = (lane & 3)*8;
  const u16* as = Ap + (size_t)(m0 + srow)*256 + sk;
  const u16* bs = Btp + (size_t)srow*256 + sk;
  auto stage = [&](int kw, int buf){
    char* dA = base + buf*8192;
    char* dB = base + 16384 + buf*8192;
    gload16(as + kw*32,            dA + wv*1024);
    gload16(as + 64*256 + kw*32,   dA + 4096 + wv*1024);
    gload16(bs + kw*32,            dB + wv*1024);
    gload16(bs + 64*256 + kw*32,   dB + 4096 + wv*1024);
  };
  stage(0, 0);
  floatx4 acc[4][4] = {};
  for (int kw = 0; kw < 8; ++kw){
    __syncthreads();
    if (kw < 7) stage(kw + 1, (kw + 1) & 1);
    const char* Ac = base + (kw & 1)*8192;
    const char* Bc = base + 16384 + (kw & 1)*8192;
    short8 a[4], b[4];
#pragma unroll
    for (int i = 0; i < 4; ++i)
      a[i] = *(const short8*)(Ac + (wr*64 + i*16 + lane15)*64 + quad*16);
#pragma unroll
    for (int j = 0; j < 4; ++j)
      b[j] = *(const short8*)(Bc + (wc*64 + j*16 + lane15)*64 + quad*16);
#pragma unroll
    for (int i = 0; i < 4; ++i)
#pragma unroll
      for (int j = 0; j < 4; ++j)
        acc[i][j] = __builtin_amdgcn_mfma_f32_16x16x32_bf16(b[j], a[i], acc[i][j], 0, 0, 0);
  }
  // epilogue: bias, optional per-head L2 norm (swapped map: lane15->row, quad*4+r->col)
#pragma unroll
  for (int j = 0; j < 4; ++j){
    floatx4 bz = *(const floatx4*)(bp + wc*64 + j*16 + quad*4);
#pragma unroll
    for (int i = 0; i < 4; ++i) acc[i][j] += bz;
  }
  if (nrm){
#pragma unroll
    for (int i = 0; i < 4; ++i)
#pragma unroll
      for (int jp = 0; jp < 2; ++jp){
        floatx4 s2 = acc[i][jp*2]*acc[i][jp*2] + acc[i][jp*2+1]*acc[i][jp*2+1];
        float ss = (s2.x + s2.y) + (s2.z + s2.w);
        ss = redq(ss);
        float inv = 1.f / fmaxf(sqrtf(ss), 1e-12f);
        acc[i][jp*2]   *= inv;
        acc[i][jp*2+1] *= inv;
      }
  }
  __syncthreads();    // staging reads done; reuse smem as C-tile [128][136]
#pragma unroll
  for (int i = 0; i < 4; ++i){
    int rl = wr*64 + i*16 + lane15;
#pragma unroll
    for (int j = 0; j < 4; ++j){
      int col = wc*64 + j*16 + quad*4;
      uintx2 w;
      w.x = pk2(acc[i][j][0], acc[i][j][1]);
      w.y = pk2(acc[i][j][2], acc[i][j][3]);
      *(uintx2*)(smem + rl*136 + col) = w;
    }
  }
  __syncthreads();
  const int r0 = tid >> 4, seg = tid & 15;
#pragma unroll
  for (int it = 0; it < 8; ++it){
    int r = it*16 + r0;
    uintx4 w = *(const uintx4*)(smem + r*136 + seg*8);
    *(uintx4*)(C + (size_t)(m0 + r)*Nst + sl*128 + seg*8) = w;
  }
}

// ---------------- proj GEMM: Cout[M,256](f32) = Ab[M,256](bf16) @ Bt^T + bias ----------------
__launch_bounds__(256, 3)
__global__ void gemm_proj(const u16* __restrict__ Ab, const u16* __restrict__ Bt,
                          const float* __restrict__ bias, float* __restrict__ Cout){
  __shared__ __align__(16) u16 lsA[2][4096];   // [buf][128 rows][32 k]
  __shared__ __align__(16) u16 lsB[2][8192];   // [buf][256 rows][32 k]
  const int tid = threadIdx.x, lane = tid & 63, wv = tid >> 6;
  const int lane15 = lane & 15, quad = lane >> 4;
  const int wr = wv >> 1, wc = wv & 1;     // wave = 64 rows x 128 cols
  const int m0 = blockIdx.x * 128;
  const int srow = wv*16 + (lane >> 2), sk = (lane & 3)*8;
  const u16* as = Ab + (size_t)(m0 + srow)*256 + sk;
  const u16* bs = Bt + (size_t)srow*256 + sk;
  auto stage = [&](int kw, int buf){
    char* dA = (char*)lsA[buf]; char* dB = (char*)lsB[buf];
    gload16(as + kw*32,             dA + wv*1024);
    gload16(as + 64*256 + kw*32,    dA + 4096  + wv*1024);
    gload16(bs + kw*32,             dB + wv*1024);
    gload16(bs + 64*256 + kw*32,    dB + 4096  + wv*1024);
    gload16(bs + 128*256 + kw*32,   dB + 8192  + wv*1024);
    gload16(bs + 192*256 + kw*32,   dB + 12288 + wv*1024);
  };
  stage(0, 0);
  floatx4 acc[4][8] = {};
  for (int kw = 0; kw < 8; ++kw){
    __syncthreads();
    if (kw < 7) stage(kw + 1, (kw + 1) & 1);
    const char* Ac = (const char*)lsA[kw & 1];
    const char* Bc = (const char*)lsB[kw & 1];
    short8 a[4], b[8];
#pragma unroll
    for (int i = 0; i < 4; ++i)
      a[i] = *(const short8*)(Ac + (wr*64 + i*16 + lane15)*64 + quad*16);
#pragma unroll
    for (int j = 0; j < 8; ++j)
      b[j] = *(const short8*)(Bc + (wc*128 + j*16 + lane15)*64 + quad*16);
#pragma unroll
    for (int i = 0; i < 4; ++i)
#pragma unroll
      for (int j = 0; j < 8; ++j)
        acc[i][j] = __builtin_amdgcn_mfma_f32_16x16x32_bf16(b[j], a[i], acc[i][j], 0, 0, 0);
  }
#pragma unroll
  for (int i = 0; i < 4; ++i){
    int row = m0 + wr*64 + i*16 + lane15;
#pragma unroll
    for (int j = 0; j < 8; ++j){
      int colb = wc*128 + j*16 + quad*4;
      floatx4 bz = *(const floatx4*)(bias + colb);
      floatx4 o = acc[i][j] + bz;
      *(floatx4*)(Cout + (size_t)row*256 + colb) = o;
    }
  }
}

// ---------------- window attention (S^T formulation), full image ----------------
// qkvh: [65536][384] bf16, Qn[0,128) Kn[128,256) V[256,384); grid (256 windows, 4 heads)
// VT oct stride padded 256->264 u16 (write banks cover all 32).
__launch_bounds__(256, 3)
__global__ void win_attn(const u16* __restrict__ qkvh, const float* __restrict__ lsw,
                         const float* __restrict__ biasw, u16* __restrict__ outm){
  __shared__ __align__(16) u16 sm[24832];   // K[0,8192) Q[8192,16384)->P  VT[16384, 16384+32*264)
  const int tid = threadIdx.x, lane = tid & 63, wv = tid >> 6;
  const int lane15 = lane & 15, quad = lane >> 4;
  const int h = blockIdx.y;
  const int wyl = blockIdx.x >> 4, wx = blockIdx.x & 15;
  u16* Ks = sm;
  u16* Qs = sm + 8192;
  u16* VT = sm + 16384;
  { // stage: DMA Q,K (pre-normalized) into k-outer [kq][256 tok][8]; V scalar-transposed
    int tok = wv*64 + lane;
    int row = (wyl*16 + (tok >> 4))*256 + wx*16 + (tok & 15);
    const char* src = (const char*)qkvh + (size_t)row*768 + h*64;
#pragma unroll
    for (int kq = 0; kq < 4; ++kq){
      gload16(src + kq*16,        (char*)Qs + wv*1024 + kq*4096);
      gload16(src + 256 + kq*16,  (char*)Ks + wv*1024 + kq*4096);
    }
    int vrow = (wyl*16 + (tid >> 4))*256 + wx*16 + (tid & 15);
    const uintx4* vp = (const uintx4*)((const char*)qkvh + (size_t)vrow*768 + 512 + h*64);
    uintx4 v0 = vp[0], v1 = vp[1], v2 = vp[2], v3 = vp[3];
    unsigned int w[16] = {v0.x,v0.y,v0.z,v0.w, v1.x,v1.y,v1.z,v1.w,
                          v2.x,v2.y,v2.z,v2.w, v3.x,v3.y,v3.z,v3.w};
    u16* vd = VT + (tid >> 3)*264 + (tid & 7);
#pragma unroll
    for (int c = 0; c < 16; ++c){
      vd[(c*2)*8]   = (u16)(w[c] & 0xffffu);
      vd[(c*2+1)*8] = (u16)(w[c] >> 16);
    }
  }
  __syncthreads();
  short8 qf[4];                 // wave owns queries wv*64 .. +63 (B-operand)
#pragma unroll
  for (int j = 0; j < 4; ++j)
    qf[j] = *(const short8*)(Qs + quad*2048 + (wv*64 + j*16 + lane15)*8);
  __syncthreads();              // all Q reads done before P overwrites

  float scale = exp2f(fminf(lsw[h], 4.6051702f) * LOG2E) * LOG2E;
  u16* Pw = Qs + wv*2048;       // per-wave P^T: [4 key-octs][64 queries][8]
  const floatx4 zf4 = {0.f, 0.f, 0.f, 0.f};
  floatx4 accO[2][4] = {};      // O^T: [d-tile][query-tile]
  float lsum[4] = {};

  for (int kc = 0; kc < 8; ++kc){      // 32 keys per chunk
    floatx4 bia[2][4];
#pragma unroll
    for (int i = 0; i < 2; ++i)
#pragma unroll
      for (int j = 0; j < 4; ++j)
        bia[i][j] = *(const floatx4*)(biasw + ((((h*8 + kc)*2 + i)*4 + quad) << 10)
                                            + ((wv*64 + j*16 + lane15) << 2));
    short8 kf[2];
#pragma unroll
    for (int i = 0; i < 2; ++i)
      kf[i] = *(const short8*)(Ks + quad*2048 + (kc*32 + i*16 + lane15)*8);
#pragma unroll
    for (int i = 0; i < 2; ++i)
#pragma unroll
      for (int j = 0; j < 4; ++j){
        floatx4 sv = __builtin_amdgcn_mfma_f32_16x16x32_bf16(kf[i], qf[j], zf4, 0, 0, 0);
        float p0 = exp2f(fmaf(sv[0], scale, bia[i][j][0]));
        float p1 = exp2f(fmaf(sv[1], scale, bia[i][j][1]));
        float p2 = exp2f(fmaf(sv[2], scale, bia[i][j][2]));
        float p3 = exp2f(fmaf(sv[3], scale, bia[i][j][3]));
        lsum[j] += (p0 + p1) + (p2 + p3);
        uintx2 w; w.x = pk2(p0, p1); w.y = pk2(p2, p3);
        *(uintx2*)(Pw + (i*2 + (quad>>1))*512 + (j*16 + lane15)*8 + (quad&1)*4) = w;
      }
    asm volatile("s_waitcnt lgkmcnt(0)" ::: "memory");
    short8 ptf[4], vtf[2];
#pragma unroll
    for (int j = 0; j < 4; ++j)
      ptf[j] = *(const short8*)(Pw + quad*512 + (j*16 + lane15)*8);
#pragma unroll
    for (int m = 0; m < 2; ++m)
      vtf[m] = *(const short8*)(VT + (kc*4 + quad)*264 + (m*16 + lane15)*8);
#pragma unroll
    for (int m = 0; m < 2; ++m)
#pragma unroll
      for (int j = 0; j < 4; ++j)
        accO[m][j] = __builtin_amdgcn_mfma_f32_16x16x32_bf16(vtf[m], ptf[j], accO[m][j], 0, 0, 0);
  }
  float linv[4];
#pragma unroll
  for (int j = 0; j < 4; ++j) linv[j] = 1.f / redq(lsum[j]);
#pragma unroll
  for (int m = 0; m < 2; ++m)
#pragma unroll
    for (int j = 0; j < 4; ++j){
      int tok = wv*64 + j*16 + lane15;
      int py = wyl*16 + (tok >> 4), px = wx*16 + (tok & 15);
      floatx4 o = accO[m][j] * linv[j];
      uintx2 w; w.x = pk2(o[0], o[1]); w.y = pk2(o[2], o[3]);
      *(uintx2*)(outm + (size_t)(py*256 + px)*256 + h*32 + m*16 + quad*4) = w;
    }
}

// ---------------- stripe phase 1: xm partials (key-split), full image ----------------
// grid (64 stripes, 4 heads, 2 key-halves). VT: oct stride 272, dh offset 136.
__launch_bounds__(256, 3)
__global__ void stripe_xm(const u16* __restrict__ qkvh, const u16* __restrict__ anchor,
                          const float* __restrict__ ls1, const float* __restrict__ bias1,
                          float* __restrict__ gl1, u16* __restrict__ gO){
  __shared__ __align__(16) u16 sm[22784];  // ANC[0,2048) KC0[2048,6144) KC1[6144,10240) VT[10240,14592) P1T[14592,22784)
  const int tid = threadIdx.x, lane = tid & 63, wv = tid >> 6;
  const int lane15 = lane & 15, quad = lane >> 4;
  const int s = blockIdx.x, h = blockIdx.y, kb = blockIdx.z;
  const int syl = s >> 3, sx = s & 7;
  u16* ANC = sm; u16* VT = sm + 10240; u16* P1T = sm + 14592;
  if (wv == 0){   // anchors pre-normalized in anch
    int ay = syl*8 + (lane >> 3), ax = sx*8 + (lane & 7);
    const char* asrc = (const char*)anchor + (size_t)(ay*64 + ax)*256 + h*64;
#pragma unroll
    for (int kq = 0; kq < 4; ++kq)
      gload16(asrc + kq*16, (char*)ANC + kq*1024);
  }
  auto stageK = [&](int kc){
    int kkb = kb*512 + kc*128;
    char* KC = (char*)sm + 4096 + (kc & 1)*8192;
#pragma unroll
    for (int hf = 0; hf < 2; ++hf){
      int tok = kkb + hf*64 + lane;
      int row = (syl*32 + (tok >> 5))*256 + sx*32 + (tok & 31);
      gload16((const char*)qkvh + (size_t)row*768 + 256 + h*64 + wv*16,
              KC + wv*2048 + hf*1024);
    }
  };
  stageK(0);
  float scale1 = exp2f(fminf(ls1[h], 4.6051702f) * LOG2E) * LOG2E;
  const floatx4 zf4 = {0.f, 0.f, 0.f, 0.f};
  floatx4 accO1[2] = {};
  float l1 = 0.f;
  for (int kc = 0; kc < 4; ++kc){
    int kkb = kb*512 + kc*128;
    { // stage V(kc): token tid>>1, d-half tid&1; direct u16 transpose
      int tok_l = tid >> 1, dh = tid & 1;
      int tok = kkb + tok_l;
      int row = (syl*32 + (tok >> 5))*256 + sx*32 + (tok & 31);
      const uintx4* vp = (const uintx4*)((const char*)qkvh + (size_t)row*768 + 512 + h*64 + dh*32);
      uintx4 v0 = vp[0], v1 = vp[1];
      unsigned int w[8] = {v0.x,v0.y,v0.z,v0.w, v1.x,v1.y,v1.z,v1.w};
      u16* vd = VT + (tok_l >> 3)*272 + dh*136 + (tok_l & 7);
#pragma unroll
      for (int c = 0; c < 8; ++c){
        vd[(c*2)*8]   = (u16)(w[c] & 0xffffu);
        vd[(c*2+1)*8] = (u16)(w[c] >> 16);
      }
    }
    __syncthreads();                       // VT visible; KC(kc) DMA drained; ANC ready
    if (kc < 3) stageK(kc + 1);            // overlaps compute, drains at end barrier
    const u16* KC = sm + 2048 + (kc & 1)*4096;
    short8 ancf = *(const short8*)(ANC + quad*512 + (wv*16 + lane15)*8);
    floatx4 bia[8];
#pragma unroll
    for (int i = 0; i < 8; ++i)
      bia[i] = *(const floatx4*)(bias1 + (((h*64 + kb*32 + kc*8 + i)*4 + quad) << 8)
                                       + ((wv*16 + lane15) << 2));
#pragma unroll
    for (int i = 0; i < 8; ++i){
      short8 kf = *(const short8*)(KC + quad*1024 + (i*16 + lane15)*8);
      floatx4 sv = __builtin_amdgcn_mfma_f32_16x16x32_bf16(kf, ancf, zf4, 0, 0, 0);
      float p0 = exp2f(fmaf(sv[0], scale1, bia[i][0]));
      float p1 = exp2f(fmaf(sv[1], scale1, bia[i][1]));
      float p2 = exp2f(fmaf(sv[2], scale1, bia[i][2]));
      float p3 = exp2f(fmaf(sv[3], scale1, bia[i][3]));
      l1 += (p0 + p1) + (p2 + p3);
      uintx2 w; w.x = pk2(p0, p1); w.y = pk2(p2, p3);
      *(uintx2*)(P1T + (i*2 + (quad>>1))*512 + (wv*16 + lane15)*8 + (quad&1)*4) = w;
    }
    asm volatile("s_waitcnt lgkmcnt(0)" ::: "memory");
#pragma unroll
    for (int ks = 0; ks < 4; ++ks){
      short8 ptf = *(const short8*)(P1T + (ks*4 + quad)*512 + (wv*16 + lane15)*8);
#pragma unroll
      for (int m = 0; m < 2; ++m){
        short8 vtf = *(const short8*)(VT + (ks*4 + quad)*272 + m*136 + lane15*8);
        accO1[m] = __builtin_amdgcn_mfma_f32_16x16x32_bf16(vtf, ptf, accO1[m], 0, 0, 0);
      }
    }
    __syncthreads();   // protect VT/P1T before next-iter staging
  }
  l1 = redq(l1);
  int ent = (s*4 + h)*2 + kb;
  if (quad == 0) gl1[ent*64 + wv*16 + lane15] = l1;
#pragma unroll
  for (int m = 0; m < 2; ++m){
    uintx2 w; w.x = pk2(accO1[m][0], accO1[m][1]); w.y = pk2(accO1[m][2], accO1[m][3]);
    *(uintx2*)(gO + (size_t)ent*2048 + (wv*16 + lane15)*32 + m*16 + quad*4) = w;
  }
}

// ---------------- stripe phase 2: xs, full image ----------------
// grid (64 stripes * 4 query-chunks, 4 heads)
__launch_bounds__(256, 3)
__global__ void stripe_xs(const u16* __restrict__ qkvh, const u16* __restrict__ anchor,
                          const float* __restrict__ ls2, const float* __restrict__ bias2,
                          const float* __restrict__ gl1, const u16* __restrict__ gO,
                          u16* __restrict__ outm){
  __shared__ __align__(16) u16 sm[20480]; // ANC[0,2048) XMT[2048,4096) QW[4096+wv*2048) P2T[12288+wv*2048)
  const int tid = threadIdx.x, lane = tid & 63, wv = tid >> 6;
  const int lane15 = lane & 15, quad = lane >> 4;
  const int s = blockIdx.x >> 2, qc = blockIdx.x & 3, h = blockIdx.y;
  const int syl = s >> 3, sx = s & 7;
  u16* ANC = sm;
  u16* XMT = sm + 2048;
  u16* QW  = sm + 4096 + wv*2048;
  u16* P2T = sm + 12288 + wv*2048;
  if (wv == 0){
    int ay = syl*8 + (lane >> 3), ax = sx*8 + (lane & 7);
    const char* asrc = (const char*)anchor + (size_t)(ay*64 + ax)*256 + h*64;
#pragma unroll
    for (int kq = 0; kq < 4; ++kq)
      gload16(asrc + kq*16, (char*)ANC + kq*1024);
  }
  { // combine xm partials -> XMT [anchor-oct][d 32][8] bf16
    int a = tid >> 2, db = (tid & 3)*8;
    int e0 = (s*4 + h)*2;
    float inv = 1.f / (gl1[e0*64 + a] + gl1[(e0 + 1)*64 + a]);
    uintx4 u0 = *(const uintx4*)(gO + (size_t)e0*2048 + a*32 + db);
    uintx4 u1 = *(const uintx4*)(gO + (size_t)(e0 + 1)*2048 + a*32 + db);
    unsigned int w0[4] = {u0.x, u0.y, u0.z, u0.w};
    unsigned int w1[4] = {u1.x, u1.y, u1.z, u1.w};
#pragma unroll
    for (int c = 0; c < 4; ++c){
      float a0 = bf2f((u16)(w0[c] & 0xffffu)) + bf2f((u16)(w1[c] & 0xffffu));
      float a1 = bf2f((u16)(w0[c] >> 16))     + bf2f((u16)(w1[c] >> 16));
      XMT[(a >> 3)*256 + (db + c*2)*8     + (a & 7)] = f2bf(a0 * inv);
      XMT[(a >> 3)*256 + (db + c*2 + 1)*8 + (a & 7)] = f2bf(a1 * inv);
    }
  }
  int tq = qc*256 + wv*64;     // query base within stripe (wave owns 64)
  { // DMA stage this wave's 64 queries (pre-normalized)
    int tok = tq + lane;
    int row = (syl*32 + (tok >> 5))*256 + sx*32 + (tok & 31);
    const char* src = (const char*)qkvh + (size_t)row*768 + h*64;
#pragma unroll
    for (int kq = 0; kq < 4; ++kq)
      gload16(src + kq*16, (char*)QW + kq*1024);
  }
  __syncthreads();
  short8 qf2[4];
#pragma unroll
  for (int j = 0; j < 4; ++j)
    qf2[j] = *(const short8*)(QW + quad*512 + (j*16 + lane15)*8);
  float scale2 = exp2f(fminf(ls2[h], 4.6051702f) * LOG2E) * LOG2E;
  const floatx4 zf4 = {0.f, 0.f, 0.f, 0.f};
  floatx4 accO2[2][4] = {};
  float l2[4] = {};
#pragma unroll
  for (int c = 0; c < 2; ++c){      // 2 anchor chunks of 32
    floatx4 bia[2][4];
#pragma unroll
    for (int i = 0; i < 2; ++i)
#pragma unroll
      for (int j = 0; j < 4; ++j)
        bia[i][j] = *(const floatx4*)(bias2 + ((((h*4 + c*2 + i)*4 + quad) << 12)
                                             + ((tq + j*16 + lane15) << 2)));
    short8 af[2];
#pragma unroll
    for (int i = 0; i < 2; ++i)
      af[i] = *(const short8*)(ANC + quad*512 + (c*32 + i*16 + lane15)*8);
#pragma unroll
    for (int i = 0; i < 2; ++i)
#pragma unroll
      for (int j = 0; j < 4; ++j){
        floatx4 sv = __builtin_amdgcn_mfma_f32_16x16x32_bf16(af[i], qf2[j], zf4, 0, 0, 0);
        float p0 = exp2f(fmaf(sv[0], scale2, bia[i][j][0]));
        float p1 = exp2f(fmaf(sv[1], scale2, bia[i][j][1]));
        float p2 = exp2f(fmaf(sv[2], scale2, bia[i][j][2]));
        float p3 = exp2f(fmaf(sv[3], scale2, bia[i][j][3]));
        l2[j] += (p0 + p1) + (p2 + p3);
        uintx2 w; w.x = pk2(p0, p1); w.y = pk2(p2, p3);
        *(uintx2*)(P2T + (i*2 + (quad>>1))*512 + (j*16 + lane15)*8 + (quad&1)*4) = w;
      }
    asm volatile("s_waitcnt lgkmcnt(0)" ::: "memory");
    short8 ptf[4], xmf[2];
#pragma unroll
    for (int j = 0; j < 4; ++j)
      ptf[j] = *(const short8*)(P2T + quad*512 + (j*16 + lane15)*8);
#pragma unroll
    for (int m = 0; m < 2; ++m)
      xmf[m] = *(const short8*)(XMT + (c*4 + quad)*256 + (m*16 + lane15)*8);
#pragma unroll
    for (int m = 0; m < 2; ++m)
#pragma unroll
      for (int j = 0; j < 4; ++j)
        accO2[m][j] = __builtin_amdgcn_mfma_f32_16x16x32_bf16(xmf[m], ptf[j], accO2[m][j], 0, 0, 0);
  }
  float linv[4];
#pragma unroll
  for (int j = 0; j < 4; ++j) linv[j] = 1.f / redq(l2[j]);
#pragma unroll
  for (int m = 0; m < 2; ++m)
#pragma unroll
    for (int j = 0; j < 4; ++j){
      int tok = tq + j*16 + lane15;
      int py = syl*32 + (tok >> 5), px = sx*32 + (tok & 31);
      floatx4 o = accO2[m][j] * linv[j];
      uintx2 w; w.x = pk2(o[0], o[1]); w.y = pk2(o[2], o[3]);
      *(uintx2*)(outm + (size_t)(py*256 + px)*256 + 128 + h*32 + m*16 + quad*4) = w;
    }
}

// ---------------- launch ----------------
extern "C" void kernel_launch(void* const* d_in, const int* in_sizes, int n_in,
                              void* d_out, int out_size, void* d_ws, size_t ws_size,
                              hipStream_t stream) {
  (void)in_sizes; (void)n_in; (void)out_size; (void)ws_size;
  const float* x        = (const float*)d_in[0];
  const float* qkv_w    = (const float*)d_in[1];
  const float* qkv_b    = (const float*)d_in[2];
  const float* anchor_w = (const float*)d_in[3];
  const float* anchor_b = (const float*)d_in[4];
  const float* ls_w     = (const float*)d_in[5];
  const float* w1_w     = (const float*)d_in[6];
  const float* b1_w     = (const float*)d_in[7];
  const float* w2_w     = (const float*)d_in[8];
  const float* ls_s1    = (const float*)d_in[9];
  const float* w1_s1    = (const float*)d_in[10];
  const float* b1_s1    = (const float*)d_in[11];
  const float* w2_s1    = (const float*)d_in[12];
  const float* ls_s2    = (const float*)d_in[13];
  const float* w1_s2    = (const float*)d_in[14];
  const float* b1_s2    = (const float*)d_in[15];
  const float* w2_s2    = (const float*)d_in[16];
  const float* proj_w   = (const float*)d_in[17];
  const float* proj_b   = (const float*)d_in[18];
  const float* table_w  = (const float*)d_in[19];
  const float* table_s  = (const float*)d_in[20];
  const int* index_w   = (const int*)d_in[21];
  const int* index_a2w = (const int*)d_in[22];
  const int* index_w2a = (const int*)d_in[23];

  // ---- workspace layout (~177 MB; ws = 256 MiB per poison-fill WRITE_SIZE) ----
  char* ws = (char*)d_ws;
  u16*   qkvhW  = (u16*)(ws + 0);                  // 65536*384 bf16 = 50331648 B
  u16*   qkvhS  = (u16*)(ws + 50331648);           // 65536*384 bf16
  u16*   mergedb= (u16*)(ws + 100663296);          // 65536*256 bf16 = 33554432 B
  u16*   xb     = (u16*)(ws + 134217728);          // 65536*256 bf16 = 33554432 B
  u16*   pooledb= (u16*)(ws + 167772160);          // 4096*256 bf16 = 2 MB
  u16*   anch   = (u16*)(ws + 169869312);          // 4096*128 bf16 = 1 MB
  u16*   qkvt   = (u16*)(ws + 170917888);          // 768*256 bf16
  u16*   anct   = (u16*)(ws + 171311104);          // 128*256 bf16
  u16*   projt  = (u16*)(ws + 171376640);          // 256*256 bf16
  float* btw    = (float*)(ws + 171507712);
  float* bts1   = (float*)(ws + 171524096);
  float* bts2   = (float*)(ws + 171548672);
  float* biasw  = (float*)(ws + 171573248);        // 4*65536 f32 = 1 MB
  float* bias1  = (float*)(ws + 172621824);        // 1 MB
  float* bias2  = (float*)(ws + 173670400);        // 1 MB
  float* gl1    = (float*)(ws + 174718976);        // 512*64 f32 = 128 KB
  u16*   gO     = (u16*)(ws + 174850048);          // 512*2048 bf16 = 2 MB (end 176947200)

  // prep: weight transposes | cpb MLP | avgpool+x->bf16 (independent, one launch)
  prep_all<<<5320, 256, 0, stream>>>(x, qkv_w, anchor_w, proj_w, table_w, table_s,
                                     w1_w, b1_w, w2_w, w1_s1, b1_s1, w2_s1,
                                     w1_s2, b1_s2, w2_s2,
                                     qkvt, anct, projt, btw, bts1, bts2, xb, pooledb);
  bias_gather<<<3072, 256, 0, stream>>>(btw, bts1, bts2, index_w, index_a2w, index_w2a,
                                        ls_w, ls_s1, ls_s2, biasw, bias1, bias2);
  // all GEMMs: y 0..2 -> W slices (Qn,Kn,V), y 3..5 -> S slices, y 6 -> anchor (x<32)
  gemm_all<<<dim3(512, 7), 256, 0, stream>>>(xb, pooledb, qkvt, anct, qkv_b, anchor_b,
                                             qkvhW, qkvhS, anch);
  win_attn<<<dim3(256, 4), 256, 0, stream>>>(qkvhW, ls_w, biasw, mergedb);
  stripe_xm<<<dim3(64, 4, 2), 256, 0, stream>>>(qkvhS, anch, ls_s1, bias1, gl1, gO);
  stripe_xs<<<dim3(256, 4), 256, 0, stream>>>(qkvhS, anch, ls_s2, bias2, gl1, gO, mergedb);
  // output projection: bf16 merged -> f32 d_out
  gemm_proj<<<512, 256, 0, stream>>>(mergedb, projt, proj_b, (float*)d_out);
}